// Round 10
// baseline (149.321 us; speedup 1.0000x reference)
//
#include <hip/hip_runtime.h>
#include <math.h>

// Problem constants (fixed: B=1, T=2048, C=768, H=12, D=64, R=32, K0=128)
static constexpr float B_SCALAR    = -7.6246189861593985f;   // -log(2048)
static constexpr float INV_TAU     = 2.8571428571428571f;    // 1/0.35
static constexpr float INV_SQRT_R  = 0.17677669529663687f;   // 1/sqrt(32)

typedef __attribute__((ext_vector_type(8))) short bf16x8;
typedef __attribute__((ext_vector_type(4))) float f32x4;

__device__ __forceinline__ unsigned short f2b(float f) {
    union { float f; unsigned int u; } v; v.f = f;
    unsigned int r = v.u + 0x7fffu + ((v.u >> 16) & 1u);
    return (unsigned short)(r >> 16);
}

typedef const __attribute__((address_space(1))) unsigned int* gp1_t;
typedef __attribute__((address_space(3))) unsigned int* lp3_t;
__device__ __forceinline__ void gload16(const unsigned short* g, unsigned short* l) {
    __builtin_amdgcn_global_load_lds((gp1_t)g, (lp3_t)l, 16, 0, 0);
}

// XOR-swizzled bf16x8 read from a row-major LDS tile with 128B rows
__device__ __forceinline__ bf16x8 frag128(const unsigned short* base, int row, int elem) {
    int byte = (row * 128 + elem * 2) ^ ((row & 7) << 4);
    return *(const bf16x8*)((const char*)base + byte);
}
// same for 384B rows (192 bf16 per row)
__device__ __forceinline__ bf16x8 frag384(const unsigned short* base, int row, int elem) {
    int byte = (row * 384 + elem * 2) ^ ((row & 7) << 4);
    return *(const bf16x8*)((const char*)base + byte);
}

// ---------------------------------------------------------------------------
// bf16 MFMA GEMM, 64x128 tile (BM=64 for 3 blocks/CU), BK=64, double-buffered
// 2-phase prefetch, XOR-swizzled LDS.
// MODE 0: QKV (KZ=1, fp32 out + bf16 copy)  MODE 1: Wz piecewise A (split-K)
// MODE 2: Wo (split-K)
// Wave (wr=wid>>1, wc=wid&1): rows wr*32+mi*16 (mi<2), cols wc*64+ni*16 (ni<4)
// ---------------------------------------------------------------------------
template<int MODE, int KZ>
__global__ __launch_bounds__(256) void gemm_mfma(
    const unsigned short* __restrict__ A0, const unsigned short* __restrict__ A1,
    const unsigned short* __restrict__ A2, const unsigned short* __restrict__ A3,
    const unsigned short* __restrict__ Bt, const float* __restrict__ bias,
    float* __restrict__ outf, unsigned short* __restrict__ outb,
    float* __restrict__ pbuf, int K, int ldo)
{
    __shared__ unsigned short As[2][64*64];    // 16 KB
    __shared__ unsigned short Bs[2][128*64];   // 32 KB
    const int tid = threadIdx.x;
    const int lane = tid & 63, wid = tid >> 6;
    const int wr = wid >> 1, wc = wid & 1;
    const int fr = lane & 15, fq = lane >> 4;
    const int n0 = blockIdx.x * 128, m0 = blockIdx.y * 64;
    const int kz = blockIdx.z;
    const int kslice = K / KZ;
    const int kbase = kz * kslice;
    const int nt = kslice / 64;

    f32x4 acc[2][4];
#pragma unroll
    for (int mi = 0; mi < 2; ++mi)
#pragma unroll
        for (int ni = 0; ni < 4; ++ni) acc[mi][ni] = (f32x4){0.f, 0.f, 0.f, 0.f};

    auto stage = [&](int buf, int k0) {
        const unsigned short* Ap;
        int k0l, ldA;
        if (MODE == 1) {
            int p = k0 / 768;
            Ap = (p == 0) ? A0 : (p == 1) ? A1 : (p == 2) ? A2 : A3;
            k0l = k0 - p * 768; ldA = 768;
        } else { Ap = A0; k0l = k0; ldA = K; }
#pragma unroll
        for (int i = 0; i < 2; ++i) {          // A: 64 rows = 512 chunks
            int cb = i * 256 + wid * 64, c = cb + lane;
            int r = c >> 3;
            int col = ((c & 7) ^ (r & 7)) * 8;
            gload16(Ap + (size_t)(m0 + r) * ldA + k0l + col, &As[buf][cb * 8]);
        }
#pragma unroll
        for (int i = 0; i < 4; ++i) {          // B: 128 rows = 1024 chunks
            int cb = i * 256 + wid * 64, c = cb + lane;
            int r = c >> 3;
            int col = ((c & 7) ^ (r & 7)) * 8;
            gload16(Bt + (size_t)(n0 + r) * K + k0 + col, &Bs[buf][cb * 8]);
        }
    };

    stage(0, kbase);
    asm volatile("s_waitcnt vmcnt(0)" ::: "memory");
    __builtin_amdgcn_s_barrier();
    __builtin_amdgcn_sched_barrier(0);

    int cur = 0;
    for (int t = 0; t < nt; ++t) {
        if (t + 1 < nt) stage(cur ^ 1, kbase + (t + 1) * 64);
#pragma unroll
        for (int kk = 0; kk < 64; kk += 32) {
            bf16x8 af[2], bfr[4];
#pragma unroll
            for (int mi = 0; mi < 2; ++mi)
                af[mi] = frag128(As[cur], wr*32 + mi*16 + fr, kk + fq*8);
#pragma unroll
            for (int ni = 0; ni < 4; ++ni)
                bfr[ni] = frag128(Bs[cur], wc*64 + ni*16 + fr, kk + fq*8);
#pragma unroll
            for (int mi = 0; mi < 2; ++mi)
#pragma unroll
                for (int ni = 0; ni < 4; ++ni)
                    acc[mi][ni] = __builtin_amdgcn_mfma_f32_16x16x32_bf16(
                        af[mi], bfr[ni], acc[mi][ni], 0, 0, 0);
        }
        asm volatile("s_waitcnt vmcnt(0)" ::: "memory");
        __builtin_amdgcn_s_barrier();
        __builtin_amdgcn_sched_barrier(0);
        cur ^= 1;
    }
#pragma unroll
    for (int mi = 0; mi < 2; ++mi)
#pragma unroll
        for (int ni = 0; ni < 4; ++ni)
#pragma unroll
            for (int v = 0; v < 4; ++v) {
                int m = m0 + wr*32 + mi*16 + fq*4 + v;
                int n = n0 + wc*64 + ni*16 + fr;
                float val = acc[mi][ni][v];
                if (KZ > 1) {
                    pbuf[((size_t)kz * 2048 + m) * 768 + n] = val;
                } else {
                    float vv = val + bias[n];
                    outf[(size_t)m * ldo + n] = vv;
                    if (MODE == 0) outb[(size_t)m * ldo + n] = f2b(vv);
                }
            }
}

// ---------------------------------------------------------------------------
// Split-K combines
// ---------------------------------------------------------------------------
__global__ __launch_bounds__(256) void wz_combine(
    const float* __restrict__ pbuf, const float* __restrict__ bz,
    const float* __restrict__ h0, const float* __restrict__ htl,
    unsigned short* __restrict__ outb)
{
    int i = blockIdx.x * 256 + threadIdx.x;
    if (i >= 2048*768/4) return;
    float4 s = *(const float4*)&pbuf[i*4];
    float4 p1 = *(const float4*)&pbuf[1536*1024 + i*4];
    float4 p2 = *(const float4*)&pbuf[2*1536*1024 + i*4];
    float4 p3 = *(const float4*)&pbuf[3*1536*1024 + i*4];
    s.x += p1.x + p2.x + p3.x; s.y += p1.y + p2.y + p3.y;
    s.z += p1.z + p2.z + p3.z; s.w += p1.w + p2.w + p3.w;
    float4 b = *(const float4*)&bz[(i % 192) * 4];
    float4 a = *(const float4*)&h0[i*4];
    float4 t = *(const float4*)&htl[i*4];
    float z0 = 1.f/(1.f+expf(-(s.x+b.x))), z1 = 1.f/(1.f+expf(-(s.y+b.y)));
    float z2 = 1.f/(1.f+expf(-(s.z+b.z))), z3 = 1.f/(1.f+expf(-(s.w+b.w)));
    outb[i*4+0] = f2b((1.f-z0)*a.x + z0*t.x);
    outb[i*4+1] = f2b((1.f-z1)*a.y + z1*t.y);
    outb[i*4+2] = f2b((1.f-z2)*a.z + z2*t.z);
    outb[i*4+3] = f2b((1.f-z3)*a.w + z3*t.w);
}

__global__ __launch_bounds__(256) void wo_combine(
    const float* __restrict__ pbuf, const float* __restrict__ bo,
    float* __restrict__ out)
{
    int i = blockIdx.x * 256 + threadIdx.x;
    if (i >= 2048*768/4) return;
    float4 s = *(const float4*)&pbuf[i*4];
    float4 p1 = *(const float4*)&pbuf[1536*1024 + i*4];
    float4 b = *(const float4*)&bo[(i % 192) * 4];
    float4 o;
    o.x = s.x + p1.x + b.x; o.y = s.y + p1.y + b.y;
    o.z = s.z + p1.z + b.z; o.w = s.w + p1.w + b.w;
    *(float4*)&out[i*4] = o;
}

// ---------------------------------------------------------------------------
// Mega-prep: x->bf16 cast, all weight transposes (fp32->bf16), bias concat.
// ---------------------------------------------------------------------------
__global__ __launch_bounds__(256) void prep_all(
    const float* __restrict__ x, unsigned short* __restrict__ xb,
    const float* __restrict__ wq, const float* __restrict__ wk,
    const float* __restrict__ wv, unsigned short* __restrict__ wqkvT,
    const float* __restrict__ wz, unsigned short* __restrict__ wzT,
    const float* __restrict__ wo, unsigned short* __restrict__ woT,
    const float* __restrict__ pq, const float* __restrict__ pk,
    const float* __restrict__ pv, unsigned short* __restrict__ pT,
    const float* __restrict__ bq, const float* __restrict__ bk,
    const float* __restrict__ bv, float* __restrict__ bqkv)
{
    __shared__ float tile[32][33];
    int b = blockIdx.x;
    if (b < 1536) {                       // cvt x -> xb
        int i = b * 256 + threadIdx.x;
        float4 v = *(const float4*)&x[i * 4];
        xb[i*4+0] = f2b(v.x); xb[i*4+1] = f2b(v.y);
        xb[i*4+2] = f2b(v.z); xb[i*4+3] = f2b(v.w);
        return;
    }
    b -= 1536;
    const float* src; unsigned short* dst; int K, N, tb;
    if (b < 1728) {                       // wq/wk/wv (576 each)
        int sel = b / 576;
        src = (sel == 0) ? wq : (sel == 1) ? wk : wv;
        dst = wqkvT + (size_t)sel * 768 * 768;
        K = 768; N = 768; tb = b - sel * 576;
    } else if (b < 4032) {                // wz (2304)
        src = wz; dst = wzT; K = 3072; N = 768; tb = b - 1728;
    } else if (b < 4608) {                // wo (576)
        src = wo; dst = woT; K = 768; N = 768; tb = b - 4032;
    } else if (b < 4680) {                // pq/pk/pv (24 each)
        int sel = (b - 4608) / 24;
        src = (sel == 0) ? pq : (sel == 1) ? pk : pv;
        dst = pT + (size_t)sel * 32 * 768;
        K = 768; N = 32; tb = (b - 4608) % 24;
    } else {                              // concat_bias (9)
        int n = (b - 4680) * 256 + threadIdx.x;
        if (n < 2304)
            bqkv[n] = (n < 768) ? bq[n] : (n < 1536) ? bk[n - 768] : bv[n - 1536];
        return;
    }
    int kt = K / 32;
    int kb = (tb % kt) * 32, nb = (tb / kt) * 32;
    int tx = threadIdx.x & 31, ty = threadIdx.x >> 5;
#pragma unroll
    for (int s = 0; s < 32; s += 8)
        tile[ty + s][tx] = src[(size_t)(kb + ty + s) * N + nb + tx];
    __syncthreads();
#pragma unroll
    for (int s = 0; s < 32; s += 8)
        dst[(size_t)(nb + ty + s) * K + kb + tx] = f2b(tile[tx][ty + s]);
}

// ---------------------------------------------------------------------------
// Low-rank projections via MFMA, split-K=4.
// grid (16 m-tiles, 3 sels, 4 kz). A = qkvb slice, B = pT[sel][32][768].
// ---------------------------------------------------------------------------
__global__ __launch_bounds__(256) void lowrank_mfma(
    const unsigned short* __restrict__ qkvb, const unsigned short* __restrict__ pT,
    float* __restrict__ pbuf)
{
    __shared__ unsigned short As[2][128*64];
    __shared__ unsigned short Bs[2][32*64];
    const int tid = threadIdx.x, lane = tid & 63, wid = tid >> 6;
    const int fr = lane & 15, fq = lane >> 4;
    const int m0 = blockIdx.x * 128;
    const int sel = blockIdx.y, kz = blockIdx.z;
    const int kbase = kz * 192;

    f32x4 acc[2][2];
#pragma unroll
    for (int mi = 0; mi < 2; ++mi)
#pragma unroll
        for (int ni = 0; ni < 2; ++ni) acc[mi][ni] = (f32x4){0.f,0.f,0.f,0.f};

    auto stage = [&](int buf, int k0) {
#pragma unroll
        for (int i = 0; i < 4; ++i) {     // A: 128x64 = 1024 chunks
            int cb = i * 256 + wid * 64, c = cb + lane;
            int r = c >> 3, col = ((c & 7) ^ (r & 7)) * 8;
            gload16(qkvb + (size_t)(m0 + r) * 2304 + sel*768 + k0 + col, &As[buf][cb * 8]);
        }
        {                                 // B: 32x64 = 256 chunks
            int cb = wid * 64, c = cb + lane;
            int r = c >> 3, col = ((c & 7) ^ (r & 7)) * 8;
            gload16(pT + (size_t)sel * 32*768 + (size_t)r * 768 + k0 + col, &Bs[buf][cb * 8]);
        }
    };

    stage(0, kbase);
    asm volatile("s_waitcnt vmcnt(0)" ::: "memory");
    __builtin_amdgcn_s_barrier();
    __builtin_amdgcn_sched_barrier(0);

    int cur = 0;
    for (int t = 0; t < 3; ++t) {
        if (t + 1 < 3) stage(cur ^ 1, kbase + (t + 1) * 64);
#pragma unroll
        for (int kk = 0; kk < 64; kk += 32) {
            bf16x8 a[2], b[2];
#pragma unroll
            for (int mi = 0; mi < 2; ++mi)
                a[mi] = frag128(As[cur], wid*32 + mi*16 + fr, kk + fq*8);
#pragma unroll
            for (int ni = 0; ni < 2; ++ni)
                b[ni] = frag128(Bs[cur], ni*16 + fr, kk + fq*8);
#pragma unroll
            for (int mi = 0; mi < 2; ++mi)
#pragma unroll
                for (int ni = 0; ni < 2; ++ni)
                    acc[mi][ni] = __builtin_amdgcn_mfma_f32_16x16x32_bf16(
                        a[mi], b[ni], acc[mi][ni], 0, 0, 0);
        }
        asm volatile("s_waitcnt vmcnt(0)" ::: "memory");
        __builtin_amdgcn_s_barrier();
        __builtin_amdgcn_sched_barrier(0);
        cur ^= 1;
    }
#pragma unroll
    for (int mi = 0; mi < 2; ++mi)
#pragma unroll
        for (int ni = 0; ni < 2; ++ni)
#pragma unroll
            for (int v = 0; v < 4; ++v) {
                int m = m0 + wid*32 + mi*16 + fq*4 + v;
                int n = ni*16 + fr;
                pbuf[((size_t)(kz*3 + sel) * 2048 + m) * 32 + n] = acc[mi][ni][v];
            }
}

// ---------------------------------------------------------------------------
// Fused lowrank_finish + cummax: blocks 0-511 do qr/kr; blocks 512-543 do
// the Vr column (sum partials, inclusive cummax scan, evtb, ms). vr buffer gone.
// ---------------------------------------------------------------------------
__global__ __launch_bounds__(256) void lowrank_post(
    const float* __restrict__ pbuf,
    unsigned short* __restrict__ qrb, unsigned short* __restrict__ krb,
    unsigned short* __restrict__ evtb, float* __restrict__ ms)
{
    int b = blockIdx.x, tid = threadIdx.x;
    if (b < 512) {                               // qr (sel 0) / kr (sel 1)
        int idx = b * 256 + tid;                 // [0, 131072)
        int sel = idx >> 16, rem = idx & 65535;
        float s = pbuf[(size_t)(0*3 + sel)*65536 + rem]
                + pbuf[(size_t)(1*3 + sel)*65536 + rem]
                + pbuf[(size_t)(2*3 + sel)*65536 + rem]
                + pbuf[(size_t)(3*3 + sel)*65536 + rem];
        if (sel == 0) qrb[rem] = f2b(s * INV_SQRT_R);
        else          krb[rem] = f2b(s);
        return;
    }
    // Vr column r: sum 4 partials per t, running cummax, exp
    __shared__ float part[256];
    int r = b - 512;
    int t0 = tid * 8;
    float sv[8], v[8];
    float run = -INFINITY;
#pragma unroll
    for (int e = 0; e < 8; ++e) {
        int t = t0 + e;
        float s = pbuf[(size_t)(0*3 + 2)*65536 + t*32 + r]
                + pbuf[(size_t)(1*3 + 2)*65536 + t*32 + r]
                + pbuf[(size_t)(2*3 + 2)*65536 + t*32 + r]
                + pbuf[(size_t)(3*3 + 2)*65536 + t*32 + r];
        sv[e] = s;
        run = fmaxf(run, s);
        v[e] = run;
    }
    part[tid] = run;
    __syncthreads();
    for (int off = 1; off < 256; off <<= 1) {
        float other = (tid >= off) ? part[tid - off] : -INFINITY;
        __syncthreads();
        part[tid] = fmaxf(part[tid], other);
        __syncthreads();
    }
    float excl = (tid > 0) ? part[tid - 1] : -INFINITY;
#pragma unroll
    for (int e = 0; e < 8; ++e) {
        int t = t0 + e;
        ms[t*32 + r] = fmaxf(v[e], excl);
        evtb[(size_t)r * 2048 + t] = f2b(expf(sv[e]));
    }
}

// ---------------------------------------------------------------------------
// Seed attention, MFMA flash-style. grid (16 i-tiles, 16 j-chunks), jc<=it.
// ---------------------------------------------------------------------------
__global__ __launch_bounds__(256) void seed_mfma(
    const unsigned short* __restrict__ qrb, const unsigned short* __restrict__ krb,
    const unsigned short* __restrict__ evtb, float* __restrict__ partial)
{
    int it = blockIdx.x, jc = blockIdx.y;
    if (jc > it) return;
    const int i0 = it * 128, j0 = jc * 128;
    __shared__ unsigned short Qs[128*32];
    __shared__ unsigned short Ks[128*32];
    __shared__ unsigned short Es[32*128];
    __shared__ unsigned short Ps[128*128];
    const int tid = threadIdx.x, lane = tid & 63, wid = tid >> 6;
    const int fr = lane & 15, fq = lane >> 4;

#pragma unroll
    for (int s = 0; s < 2; ++s) {
        int cb = s * 256 + wid * 64;
        int c = cb + lane;
        int r = c >> 2, col = (c & 3) * 8;
        gload16(qrb + (size_t)(i0 + r) * 32 + col, &Qs[cb * 8]);
        gload16(krb + (size_t)(j0 + r) * 32 + col, &Ks[cb * 8]);
    }
#pragma unroll
    for (int s = 0; s < 2; ++s) {
        int c = s * 256 + tid;
        int rr = c >> 4, cc = c & 15;
        bf16x8 v = *(const bf16x8*)&evtb[(size_t)rr * 2048 + j0 + cc * 8];
        int byte = (rr * 256 + cc * 16) ^ ((rr & 7) << 4);
        *(bf16x8*)((char*)Es + byte) = v;
    }
    __syncthreads();

    const int wr = wid >> 1, wc = wid & 1;
    bf16x8 af[4], bk[4];
#pragma unroll
    for (int mi = 0; mi < 4; ++mi)
        af[mi] = *(const bf16x8*)&Qs[(wr*64 + mi*16 + fr)*32 + fq*8];
#pragma unroll
    for (int ni = 0; ni < 4; ++ni)
        bk[ni] = *(const bf16x8*)&Ks[(wc*64 + ni*16 + fr)*32 + fq*8];
#pragma unroll
    for (int mi = 0; mi < 4; ++mi)
#pragma unroll
        for (int ni = 0; ni < 4; ++ni) {
            f32x4 s4 = __builtin_amdgcn_mfma_f32_16x16x32_bf16(
                af[mi], bk[ni], (f32x4){0.f,0.f,0.f,0.f}, 0, 0, 0);
#pragma unroll
            for (int v = 0; v < 4; ++v) {
                int row = wr*64 + mi*16 + fq*4 + v;
                int col = wc*64 + ni*16 + fr;
                float a = 0.f;
                if (j0 + col <= i0 + row) {
                    float s = s4[v];
                    a = 1.f / (1.f + expf(-(s*s + B_SCALAR)));
                }
                int byte = (row * 256 + col * 2) ^ ((row & 7) << 4);
                *(unsigned short*)((char*)Ps + byte) = f2b(a);
            }
        }
    __syncthreads();

    f32x4 yacc[2][2];
#pragma unroll
    for (int mi = 0; mi < 2; ++mi)
#pragma unroll
        for (int nf = 0; nf < 2; ++nf) yacc[mi][nf] = (f32x4){0.f,0.f,0.f,0.f};
#pragma unroll
    for (int ks = 0; ks < 4; ++ks) {
        bf16x8 pa[2], eb[2];
#pragma unroll
        for (int mi = 0; mi < 2; ++mi) {
            int row = wid*32 + mi*16 + fr;
            int byte = (row * 256 + ks * 64 + fq * 16) ^ ((row & 7) << 4);
            pa[mi] = *(const bf16x8*)((const char*)Ps + byte);
        }
#pragma unroll
        for (int nf = 0; nf < 2; ++nf) {
            int rrow = nf*16 + fr;
            int byte = (rrow * 256 + ks * 64 + fq * 16) ^ ((rrow & 7) << 4);
            eb[nf] = *(const bf16x8*)((const char*)Es + byte);
        }
#pragma unroll
        for (int mi = 0; mi < 2; ++mi)
#pragma unroll
            for (int nf = 0; nf < 2; ++nf)
                yacc[mi][nf] = __builtin_amdgcn_mfma_f32_16x16x32_bf16(
                    pa[mi], eb[nf], yacc[mi][nf], 0, 0, 0);
    }
    float* pout = partial + ((size_t)(it*16 + jc) * 128) * 32;
#pragma unroll
    for (int mi = 0; mi < 2; ++mi)
#pragma unroll
        for (int nf = 0; nf < 2; ++nf)
#pragma unroll
            for (int v = 0; v < 4; ++v) {
                int row = wid*32 + mi*16 + fq*4 + v;
                int col = nf*16 + fr;
                pout[row*32 + col] = yacc[mi][nf][v];
            }
}

// ---------------------------------------------------------------------------
// Fused: reduce seed partials + LASER log + H0 = Lr @ up_w (+ bf16 copy).
// ---------------------------------------------------------------------------
__global__ __launch_bounds__(256) void seed_up(
    const float* __restrict__ partial, const float* __restrict__ ms,
    const float* __restrict__ up, float* __restrict__ h0,
    unsigned short* __restrict__ h0b)
{
    __shared__ float ls[32];
    int t = blockIdx.x, tid = threadIdx.x;
    if (tid < 32) {
        int r = tid;
        int it = t >> 7, row = t & 127;
        float y = 0.f;
        for (int jjc = 0; jjc <= it; ++jjc)
            y += partial[(((size_t)(it*16 + jjc) * 128) + row) * 32 + r];
        float m = ms[t*32 + r];
        ls[r] = logf(fmaxf(y * expf(-m), 1e-30f)) + m;
    }
    __syncthreads();
    for (int c = tid; c < 768; c += 256) {
        float acc = 0.f;
#pragma unroll
        for (int rr = 0; rr < 32; ++rr) acc = fmaf(ls[rr], up[rr*768 + c], acc);
        h0[(size_t)t*768 + c] = acc;
        h0b[(size_t)t*768 + c] = f2b(acc);
    }
}

// ---------------------------------------------------------------------------
// Fused head-norms + sliding-window max. Task-mapped single dispatch:
// blocks [0,6144): per-(t,h) L2 norms (4 wave-tasks/block)
// blocks [6144,6528): slide_max tiles (c0 = (b%12)*64, t0 = (b/12)*64)
// ---------------------------------------------------------------------------
__global__ __launch_bounds__(256) void norms_slide(
    const float* __restrict__ qkv,
    unsigned short* __restrict__ qhatb, unsigned short* __restrict__ khatb,
    float* __restrict__ mnear, unsigned short* __restrict__ vexptb)
{
    __shared__ float vs[192][64];
    int b = blockIdx.x, tid = threadIdx.x;
    if (b < 6144) {                              // head norms
        int w = b * 4 + (tid >> 6);              // [0, 24576) = 2048*12
        int lane = tid & 63;
        int t = w / 12, h = w - t * 12;
        float q = qkv[t*2304 + h*64 + lane];
        float k = qkv[t*2304 + 768 + h*64 + lane];
        float sq = q*q, sk = k*k;
#pragma unroll
        for (int off = 32; off; off >>= 1) { sq += __shfl_xor(sq, off); sk += __shfl_xor(sk, off); }
        float iq = 1.f / fmaxf(sqrtf(sq), 1e-12f);
        float ik = 1.f / fmaxf(sqrtf(sk), 1e-12f);
        qhatb[(size_t)t*768 + h*64 + lane] = f2b(q * iq);
        khatb[(size_t)t*768 + h*64 + lane] = f2b(k * ik);
        return;
    }
    b -= 6144;
    int c0 = (b % 12) * 64, t0 = (b / 12) * 64;
#pragma unroll
    for (int s = 0; s < 12; ++s) {
        int idx = tid + s * 256;
        int rr = idx >> 4, c4 = (idx & 15) * 4;
        int t = t0 - 128 + rr;
        float4 v4;
        if (t < 0) v4 = make_float4(-INFINITY, -INFINITY, -INFINITY, -INFINITY);
        else       v4 = *(const float4*)&qkv[t*2304 + 1536 + c0 + c4];
        *(float4*)&vs[rr][c4] = v4;
    }
    __syncthreads();
    int c = tid & 63, tg = tid >> 6;
    const int TG = tg * 16;
    float core = -INFINITY;
    for (int s = TG + 15; s <= TG + 128; ++s) core = fmaxf(core, vs[s][c]);
    float head[16], tail[16];
    head[15] = -INFINITY;
    float hs = -INFINITY;
#pragma unroll
    for (int u = 14; u >= 0; --u) { hs = fmaxf(hs, vs[TG + u][c]); head[u] = hs; }
    tail[0] = -INFINITY;
    float ts = -INFINITY;
#pragma unroll
    for (int u = 1; u <= 15; ++u) { ts = fmaxf(ts, vs[TG + 128 + u][c]); tail[u] = ts; }
#pragma unroll
    for (int u = 0; u < 16; ++u) {
        int tl = TG + u;
        float m = fmaxf(fmaxf(core, head[u]), tail[u]);
        float v = vs[tl + 128][c];
        int t = t0 + tl;
        mnear[(size_t)t*768 + c0 + c] = m;
        vexptb[(size_t)(c0 + c) * 2048 + t] = f2b(expf(v - m));
    }
}

// ---------------------------------------------------------------------------
// Fused near-field (full MFMA): QK^T -> masked sigmoid -> P bf16 (XOR-swz LDS,
// reusing K buffer) -> PV MFMA vs transposed bf16 exp(V-m) -> log+m -> gate.
// Epilogue also emits Htilde bf16 + (H0*Htilde) bf16 for the Wz GEMM.
// grid (32 i-tiles of 64, 12 heads), block 256 (4 waves). LDS 56 KB.
// ---------------------------------------------------------------------------
__global__ __launch_bounds__(256) void near_fused(
    const unsigned short* __restrict__ qhatb, const unsigned short* __restrict__ khatb,
    const unsigned short* __restrict__ vexptb, const float* __restrict__ mnear,
    const float* __restrict__ gu, const float* __restrict__ gb,
    const float* __restrict__ h0, float* __restrict__ hn,
    unsigned short* __restrict__ htlb, unsigned short* __restrict__ prodb)
{
    __shared__ unsigned short Qs[64*64];
    __shared__ unsigned short KPs[192*64];
    __shared__ unsigned short Vst[64*192];
    const int it = blockIdx.x, hh = blockIdx.y;
    const int i0 = it * 64;
    const int tid = threadIdx.x, lane = tid & 63, wid = tid >> 6;
    const int fr = lane & 15, fq = lane >> 4;

#pragma unroll
    for (int i = 0; i < 2; ++i) {
        int cb = i * 256 + wid * 64, c = cb + lane;
        int r = c >> 3, col = ((c & 7) ^ (r & 7)) * 8;
        gload16(qhatb + (size_t)(i0 + r) * 768 + hh*64 + col, &Qs[cb * 8]);
    }
#pragma unroll
    for (int i = 0; i < 6; ++i) {
        int cb = i * 256 + wid * 64, c = cb + lane;
        int r = c >> 3, col = ((c & 7) ^ (r & 7)) * 8;
        int j = i0 - 128 + r; if (j < 0) j = 0;
        gload16(khatb + (size_t)j * 768 + hh*64 + col, &KPs[cb * 8]);
    }
#pragma unroll
    for (int i = 0; i < 6; ++i) {
        int cb = i * 256 + wid * 64, c = cb + lane;
        int d = c / 24, cc = c - d * 24;
        int ccp = (cc & 24) | ((cc & 7) ^ (d & 7));
        int t = i0 - 128 + ccp * 8; if (t < 0) t = 0;
        gload16(vexptb + (size_t)(hh*64 + d) * 2048 + t, &Vst[cb * 8]);
    }
    __syncthreads();

    f32x4 sacc[4][3];
#pragma unroll
    for (int mi = 0; mi < 4; ++mi)
#pragma unroll
        for (int ni = 0; ni < 3; ++ni) sacc[mi][ni] = (f32x4){0.f,0.f,0.f,0.f};
#pragma unroll
    for (int kt = 0; kt < 2; ++kt) {
        int kk = kt * 32;
        bf16x8 qa[4], kb[3];
#pragma unroll
        for (int mi = 0; mi < 4; ++mi)
            qa[mi] = frag128(Qs, mi*16 + fr, kk + fq*8);
#pragma unroll
        for (int ni = 0; ni < 3; ++ni)
            kb[ni] = frag128(KPs, wid*48 + ni*16 + fr, kk + fq*8);
#pragma unroll
        for (int mi = 0; mi < 4; ++mi)
#pragma unroll
            for (int ni = 0; ni < 3; ++ni)
                sacc[mi][ni] = __builtin_amdgcn_mfma_f32_16x16x32_bf16(
                    qa[mi], kb[ni], sacc[mi][ni], 0, 0, 0);
    }
    __syncthreads();

#pragma unroll
    for (int mi = 0; mi < 4; ++mi)
#pragma unroll
        for (int ni = 0; ni < 3; ++ni)
#pragma unroll
            for (int v = 0; v < 4; ++v) {
                int il = mi*16 + fq*4 + v;
                int jl = wid*48 + ni*16 + fr;
                float s = sacc[mi][ni][v];
                float a = 0.f;
                if (jl >= il && jl <= il + 128 && (i0 - 128 + jl) >= 0)
                    a = 1.f / (1.f + expf(-(s*s*INV_TAU + B_SCALAR)));
                int byte = (il * 384 + jl * 2) ^ ((il & 7) << 4);
                *(unsigned short*)((char*)KPs + byte) = f2b(a);
            }
    __syncthreads();

    f32x4 yacc[4];
#pragma unroll
    for (int nf = 0; nf < 4; ++nf) yacc[nf] = (f32x4){0.f,0.f,0.f,0.f};
#pragma unroll
    for (int ks = 0; ks < 6; ++ks) {
        int kk = ks * 32;
        bf16x8 pa = frag384(KPs, wid*16 + fr, kk + fq*8);
        bf16x8 vb[4];
#pragma unroll
        for (int nf = 0; nf < 4; ++nf)
            vb[nf] = frag384(Vst, nf*16 + fr, kk + fq*8);
#pragma unroll
        for (int nf = 0; nf < 4; ++nf)
            yacc[nf] = __builtin_amdgcn_mfma_f32_16x16x32_bf16(pa, vb[nf], yacc[nf], 0, 0, 0);
    }

    float hv[4][4];
    float sp[4] = {0.f, 0.f, 0.f, 0.f};
#pragma unroll
    for (int nf = 0; nf < 4; ++nf) {
        int d = nf*16 + fr;
        float guv = gu[hh*64 + d];
#pragma unroll
        for (int v = 0; v < 4; ++v) {
            int row = wid*16 + fq*4 + v;
            float y = yacc[nf][v];
            float h = logf(fmaxf(y, 1e-30f)) + mnear[(size_t)(i0 + row)*768 + hh*64 + d];
            hv[nf][v] = h;
            sp[v] = fmaf(h, guv, sp[v]);
        }
    }
#pragma unroll
    for (int off = 1; off < 16; off <<= 1) {
#pragma unroll
        for (int v = 0; v < 4; ++v) sp[v] += __shfl_xor(sp[v], off);
    }
    float gbh = gb[hh];
#pragma unroll
    for (int v = 0; v < 4; ++v) sp[v] = 1.f / (1.f + expf(-(sp[v] + gbh)));
#pragma unroll
    for (int nf = 0; nf < 4; ++nf)
#pragma unroll
        for (int v = 0; v < 4; ++v) {
            int row = wid*16 + fq*4 + v;
            int d = nf*16 + fr;
            size_t idx = (size_t)(i0 + row)*768 + hh*64 + d;
            float htl = hv[nf][v] * sp[v];
            hn[idx] = htl;
            htlb[idx] = f2b(htl);
            prodb[idx] = f2b(h0[idx] * htl);
        }
}

// ---------------------------------------------------------------------------
extern "C" void kernel_launch(void* const* d_in, const int* in_sizes, int n_in,
                              void* d_out, int out_size, void* d_ws, size_t ws_size,
                              hipStream_t stream)
{
    const float* x  = (const float*)d_in[0];
    const float* wq = (const float*)d_in[1];  const float* bq = (const float*)d_in[2];
    const float* wk = (const float*)d_in[3];  const float* bk = (const float*)d_in[4];
    const float* wv = (const float*)d_in[5];  const float* bv = (const float*)d_in[6];
    const float* wo = (const float*)d_in[7];  const float* bo = (const float*)d_in[8];
    const float* pq = (const float*)d_in[9];  const float* pk = (const float*)d_in[10];
    const float* pv = (const float*)d_in[11];
    const float* up = (const float*)d_in[12];
    const float* gu = (const float*)d_in[13]; const float* gb = (const float*)d_in[14];
    const float* wz = (const float*)d_in[15]; const float* bz = (const float*)d_in[16];
    float* out = (float*)d_out;

    float* w = (float*)d_ws;
    float* qkv  = w; w += 2048*2304;
    float* ms   = w; w += 2048*32;
    float* h0   = w; w += 2048*768;
    float* mnear= w; w += 2048*768;
    float* hn   = w; w += 2048*768;          // Htilde after near_fused
    float* partial = w; w += 16*16*128*32;   // seed partials
    float* pgemm = w; w += 4*2048*768;       // split-K partials (Wz 4 / Wo 2)
    float* plr   = w; w += 4*3*2048*32;      // lowrank split-K partials
    float* bqkv = w; w += 2304;
    unsigned short* xb     = (unsigned short*)w; w += 2048*768/2;
    unsigned short* qkvb   = (unsigned short*)w; w += 2048*2304/2;
    unsigned short* wqkvT  = (unsigned short*)w; w += 2304*768/2;
    unsigned short* wzT    = (unsigned short*)w; w += 768*3072/2;
    unsigned short* woT    = (unsigned short*)w; w += 768*768/2;
    unsigned short* pT     = (unsigned short*)w; w += 3*32*768/2;
    unsigned short* h0b    = (unsigned short*)w; w += 2048*768/2;
    unsigned short* htlb   = (unsigned short*)w; w += 2048*768/2;
    unsigned short* prodb  = (unsigned short*)w; w += 2048*768/2;
    unsigned short* houtb  = (unsigned short*)w; w += 2048*768/2;
    unsigned short* qrb    = (unsigned short*)w; w += 2048*32/2;
    unsigned short* krb    = (unsigned short*)w; w += 2048*32/2;
    unsigned short* evtb   = (unsigned short*)w; w += 32*2048/2;
    unsigned short* qhatb  = (unsigned short*)w; w += 2048*768/2;
    unsigned short* khatb  = (unsigned short*)w; w += 2048*768/2;
    unsigned short* vexptb = (unsigned short*)w; w += 768*2048/2;

    // ---- prep (single mega-dispatch)
    prep_all<<<6225, 256, 0, stream>>>(x, xb, wq, wk, wv, wqkvT, wz, wzT,
                                       wo, woT, pq, pk, pv, pT, bq, bk, bv, bqkv);

    // 0) QKV projections (fp32 + bf16 copy), BM=64: 576 blocks
    gemm_mfma<0,1><<<dim3(18,32,1), 256, 0, stream>>>(xb, nullptr, nullptr, nullptr,
        wqkvT, bqkv, qkv, qkvb, nullptr, 768, 2304);

    // 1) low-rank path
    lowrank_mfma<<<dim3(16,3,4), 256, 0, stream>>>(qkvb, pT, plr);
    lowrank_post<<<544, 256, 0, stream>>>(plr, qrb, krb, evtb, ms);
    seed_mfma<<<dim3(16,16), 256, 0, stream>>>(qrb, krb, evtb, partial);
    seed_up<<<2048, 256, 0, stream>>>(partial, ms, up, h0, h0b);

    // 2) near-field path
    norms_slide<<<6528, 256, 0, stream>>>(qkv, qhatb, khatb, mnear, vexptb);
    near_fused<<<dim3(32,12), 256, 0, stream>>>(qhatb, khatb, vexptb, mnear,
                                                gu, gb, h0, hn, htlb, prodb);

    // 3) GRU blend (split-K=4) + output projection (split-K=2), BM=64
    gemm_mfma<1,4><<<dim3(6,32,4), 256, 0, stream>>>(xb, h0b, htlb, prodb,
        wzT, nullptr, nullptr, nullptr, pgemm, 3072, 768);
    wz_combine<<<1536, 256, 0, stream>>>(pgemm, bz, h0, hn, houtb);
    gemm_mfma<2,2><<<dim3(6,32,2), 256, 0, stream>>>(houtb, nullptr, nullptr, nullptr,
        woT, nullptr, nullptr, nullptr, pgemm, 768, 768);
    wo_combine<<<1536, 256, 0, stream>>>(pgemm, bo, out);
}

// Round 11
// 148.936 us; speedup vs baseline: 1.0026x; 1.0026x over previous
//
#include <hip/hip_runtime.h>
#include <math.h>

// Problem constants (fixed: B=1, T=2048, C=768, H=12, D=64, R=32, K0=128)
static constexpr float B_SCALAR    = -7.6246189861593985f;   // -log(2048)
static constexpr float INV_TAU     = 2.8571428571428571f;    // 1/0.35
static constexpr float INV_SQRT_R  = 0.17677669529663687f;   // 1/sqrt(32)

typedef __attribute__((ext_vector_type(8))) short bf16x8;
typedef __attribute__((ext_vector_type(4))) float f32x4;

__device__ __forceinline__ unsigned short f2b(float f) {
    union { float f; unsigned int u; } v; v.f = f;
    unsigned int r = v.u + 0x7fffu + ((v.u >> 16) & 1u);
    return (unsigned short)(r >> 16);
}
__device__ __forceinline__ float b2f(unsigned short u) {
    union { unsigned int i; float f; } v; v.i = ((unsigned int)u) << 16; return v.f;
}

typedef const __attribute__((address_space(1))) unsigned int* gp1_t;
typedef __attribute__((address_space(3))) unsigned int* lp3_t;
__device__ __forceinline__ void gload16(const unsigned short* g, unsigned short* l) {
    __builtin_amdgcn_global_load_lds((gp1_t)g, (lp3_t)l, 16, 0, 0);
}

// XOR-swizzled bf16x8 read from a row-major LDS tile with 128B rows
__device__ __forceinline__ bf16x8 frag128(const unsigned short* base, int row, int elem) {
    int byte = (row * 128 + elem * 2) ^ ((row & 7) << 4);
    return *(const bf16x8*)((const char*)base + byte);
}
// same for 384B rows (192 bf16 per row)
__device__ __forceinline__ bf16x8 frag384(const unsigned short* base, int row, int elem) {
    int byte = (row * 384 + elem * 2) ^ ((row & 7) << 4);
    return *(const bf16x8*)((const char*)base + byte);
}

// ---------------------------------------------------------------------------
// bf16 MFMA GEMM, 64x128 tile, BK=64, double-buffered 2-phase prefetch,
// XOR-swizzled LDS, XCD-aware block swizzle (grids are %8==0).
// MODE 0: QKV (KZ=1, fp32 out + bf16 copy, bias)
// MODE 1: Wz, A piecewise xb|h0b|htlb|inline(h0b*htlb), split-K -> pbuf
// MODE 2: Wo (KZ=1, fp32 out + bias)
// ---------------------------------------------------------------------------
template<int MODE, int KZ>
__global__ __launch_bounds__(256) void gemm_mfma(
    const unsigned short* __restrict__ A0, const unsigned short* __restrict__ A1,
    const unsigned short* __restrict__ A2,
    const unsigned short* __restrict__ Bt, const float* __restrict__ bias,
    float* __restrict__ outf, unsigned short* __restrict__ outb,
    float* __restrict__ pbuf, int K, int ldo)
{
    __shared__ unsigned short As[2][64*64];    // 16 KB
    __shared__ unsigned short Bs[2][128*64];   // 32 KB
    const int tid = threadIdx.x;
    const int lane = tid & 63, wid = tid >> 6;
    const int wr = wid >> 1, wc = wid & 1;
    const int fr = lane & 15, fq = lane >> 4;
    // XCD-aware bijective swizzle (T1): per%8==0 for all our grids
    const int lin = blockIdx.y * gridDim.x + blockIdx.x;
    const int chunk = (gridDim.x * gridDim.y) >> 3;
    const int sw = (lin & 7) * chunk + (lin >> 3);
    const int n0 = (sw / gridDim.y) * 128, m0 = (sw % gridDim.y) * 64;
    const int kz = blockIdx.z;
    const int kslice = K / KZ;
    const int kbase = kz * kslice;
    const int nt = kslice / 64;

    f32x4 acc[2][4];
#pragma unroll
    for (int mi = 0; mi < 2; ++mi)
#pragma unroll
        for (int ni = 0; ni < 4; ++ni) acc[mi][ni] = (f32x4){0.f, 0.f, 0.f, 0.f};

    auto stage = [&](int buf, int k0) {
        if (MODE == 1 && k0 >= 2304) {
            // inline A-piece: bf16(h0b * htlb), reg-staged with same swizzle
            int k0l = k0 - 2304;
#pragma unroll
            for (int i = 0; i < 2; ++i) {
                int cb = i * 256 + wid * 64, c = cb + lane;
                int r = c >> 3, col = ((c & 7) ^ (r & 7)) * 8;
                bf16x8 a8 = *(const bf16x8*)&A1[(size_t)(m0 + r) * 768 + k0l + col];
                bf16x8 b8 = *(const bf16x8*)&A2[(size_t)(m0 + r) * 768 + k0l + col];
                bf16x8 p8;
#pragma unroll
                for (int e = 0; e < 8; ++e)
                    p8[e] = (short)f2b(b2f((unsigned short)a8[e]) * b2f((unsigned short)b8[e]));
                *(bf16x8*)&As[buf][(size_t)c * 8] = p8;
            }
        } else {
            const unsigned short* Ap;
            int k0l, ldA;
            if (MODE == 1) {
                int p = k0 / 768;
                Ap = (p == 0) ? A0 : (p == 1) ? A1 : A2;
                k0l = k0 - p * 768; ldA = 768;
            } else { Ap = A0; k0l = k0; ldA = K; }
#pragma unroll
            for (int i = 0; i < 2; ++i) {      // A: 64 rows = 512 chunks
                int cb = i * 256 + wid * 64, c = cb + lane;
                int r = c >> 3;
                int col = ((c & 7) ^ (r & 7)) * 8;
                gload16(Ap + (size_t)(m0 + r) * ldA + k0l + col, &As[buf][cb * 8]);
            }
        }
#pragma unroll
        for (int i = 0; i < 4; ++i) {          // B: 128 rows = 1024 chunks
            int cb = i * 256 + wid * 64, c = cb + lane;
            int r = c >> 3;
            int col = ((c & 7) ^ (r & 7)) * 8;
            gload16(Bt + (size_t)(n0 + r) * K + k0 + col, &Bs[buf][cb * 8]);
        }
    };

    stage(0, kbase);
    asm volatile("s_waitcnt vmcnt(0) lgkmcnt(0)" ::: "memory");
    __builtin_amdgcn_s_barrier();
    __builtin_amdgcn_sched_barrier(0);

    int cur = 0;
    for (int t = 0; t < nt; ++t) {
        if (t + 1 < nt) stage(cur ^ 1, kbase + (t + 1) * 64);
#pragma unroll
        for (int kk = 0; kk < 64; kk += 32) {
            bf16x8 af[2], bfr[4];
#pragma unroll
            for (int mi = 0; mi < 2; ++mi)
                af[mi] = frag128(As[cur], wr*32 + mi*16 + fr, kk + fq*8);
#pragma unroll
            for (int ni = 0; ni < 4; ++ni)
                bfr[ni] = frag128(Bs[cur], wc*64 + ni*16 + fr, kk + fq*8);
#pragma unroll
            for (int mi = 0; mi < 2; ++mi)
#pragma unroll
                for (int ni = 0; ni < 4; ++ni)
                    acc[mi][ni] = __builtin_amdgcn_mfma_f32_16x16x32_bf16(
                        af[mi], bfr[ni], acc[mi][ni], 0, 0, 0);
        }
        asm volatile("s_waitcnt vmcnt(0) lgkmcnt(0)" ::: "memory");
        __builtin_amdgcn_s_barrier();
        __builtin_amdgcn_sched_barrier(0);
        cur ^= 1;
    }
#pragma unroll
    for (int mi = 0; mi < 2; ++mi)
#pragma unroll
        for (int ni = 0; ni < 4; ++ni)
#pragma unroll
            for (int v = 0; v < 4; ++v) {
                int m = m0 + wr*32 + mi*16 + fq*4 + v;
                int n = n0 + wc*64 + ni*16 + fr;
                float val = acc[mi][ni][v];
                if (KZ > 1) {
                    pbuf[((size_t)kz * 2048 + m) * 768 + n] = val;
                } else {
                    float vv = val + bias[n];
                    outf[(size_t)m * ldo + n] = vv;
                    if (MODE == 0) outb[(size_t)m * ldo + n] = f2b(vv);
                }
            }
}

// ---------------------------------------------------------------------------
// Wz split-K combine + GRU blend epilogue
// ---------------------------------------------------------------------------
__global__ __launch_bounds__(256) void wz_combine(
    const float* __restrict__ pbuf, const float* __restrict__ bz,
    const float* __restrict__ h0, const float* __restrict__ htl,
    unsigned short* __restrict__ outb)
{
    int i = blockIdx.x * 256 + threadIdx.x;
    if (i >= 2048*768/4) return;
    float4 s = *(const float4*)&pbuf[i*4];
    float4 p1 = *(const float4*)&pbuf[1536*1024 + i*4];
    float4 p2 = *(const float4*)&pbuf[2*1536*1024 + i*4];
    float4 p3 = *(const float4*)&pbuf[3*1536*1024 + i*4];
    s.x += p1.x + p2.x + p3.x; s.y += p1.y + p2.y + p3.y;
    s.z += p1.z + p2.z + p3.z; s.w += p1.w + p2.w + p3.w;
    float4 b = *(const float4*)&bz[(i % 192) * 4];
    float4 a = *(const float4*)&h0[i*4];
    float4 t = *(const float4*)&htl[i*4];
    float z0 = 1.f/(1.f+expf(-(s.x+b.x))), z1 = 1.f/(1.f+expf(-(s.y+b.y)));
    float z2 = 1.f/(1.f+expf(-(s.z+b.z))), z3 = 1.f/(1.f+expf(-(s.w+b.w)));
    outb[i*4+0] = f2b((1.f-z0)*a.x + z0*t.x);
    outb[i*4+1] = f2b((1.f-z1)*a.y + z1*t.y);
    outb[i*4+2] = f2b((1.f-z2)*a.z + z2*t.z);
    outb[i*4+3] = f2b((1.f-z3)*a.w + z3*t.w);
}

// ---------------------------------------------------------------------------
// Mega-prep: x->bf16 cast, all weight transposes (fp32->bf16), bias concat.
// ---------------------------------------------------------------------------
__global__ __launch_bounds__(256) void prep_all(
    const float* __restrict__ x, unsigned short* __restrict__ xb,
    const float* __restrict__ wq, const float* __restrict__ wk,
    const float* __restrict__ wv, unsigned short* __restrict__ wqkvT,
    const float* __restrict__ wz, unsigned short* __restrict__ wzT,
    const float* __restrict__ wo, unsigned short* __restrict__ woT,
    const float* __restrict__ pq, const float* __restrict__ pk,
    const float* __restrict__ pv, unsigned short* __restrict__ pT,
    const float* __restrict__ bq, const float* __restrict__ bk,
    const float* __restrict__ bv, float* __restrict__ bqkv)
{
    __shared__ float tile[32][33];
    int b = blockIdx.x;
    if (b < 1536) {                       // cvt x -> xb
        int i = b * 256 + threadIdx.x;
        float4 v = *(const float4*)&x[i * 4];
        xb[i*4+0] = f2b(v.x); xb[i*4+1] = f2b(v.y);
        xb[i*4+2] = f2b(v.z); xb[i*4+3] = f2b(v.w);
        return;
    }
    b -= 1536;
    const float* src; unsigned short* dst; int K, N, tb;
    if (b < 1728) {                       // wq/wk/wv (576 each)
        int sel = b / 576;
        src = (sel == 0) ? wq : (sel == 1) ? wk : wv;
        dst = wqkvT + (size_t)sel * 768 * 768;
        K = 768; N = 768; tb = b - sel * 576;
    } else if (b < 4032) {                // wz (2304)
        src = wz; dst = wzT; K = 3072; N = 768; tb = b - 1728;
    } else if (b < 4608) {                // wo (576)
        src = wo; dst = woT; K = 768; N = 768; tb = b - 4032;
    } else if (b < 4680) {                // pq/pk/pv (24 each)
        int sel = (b - 4608) / 24;
        src = (sel == 0) ? pq : (sel == 1) ? pk : pv;
        dst = pT + (size_t)sel * 32 * 768;
        K = 768; N = 32; tb = (b - 4608) % 24;
    } else {                              // concat_bias (9)
        int n = (b - 4680) * 256 + threadIdx.x;
        if (n < 2304)
            bqkv[n] = (n < 768) ? bq[n] : (n < 1536) ? bk[n - 768] : bv[n - 1536];
        return;
    }
    int kt = K / 32;
    int kb = (tb % kt) * 32, nb = (tb / kt) * 32;
    int tx = threadIdx.x & 31, ty = threadIdx.x >> 5;
#pragma unroll
    for (int s = 0; s < 32; s += 8)
        tile[ty + s][tx] = src[(size_t)(kb + ty + s) * N + nb + tx];
    __syncthreads();
#pragma unroll
    for (int s = 0; s < 32; s += 8)
        dst[(size_t)(nb + ty + s) * K + kb + tx] = f2b(tile[tx][ty + s]);
}

// ---------------------------------------------------------------------------
// Packed dispatch A: lowrank_mfma (192 blocks) + norms/slide (6528 blocks)
// ---------------------------------------------------------------------------
__device__ void lowrank_body(int b, unsigned char* smem,
    const unsigned short* __restrict__ qkvb, const unsigned short* __restrict__ pT,
    float* __restrict__ pbuf)
{
    unsigned short (*As)[128*64] = (unsigned short(*)[128*64])smem;          // 32 KB
    unsigned short (*Bs)[32*64]  = (unsigned short(*)[32*64])(smem + 32768); // 8 KB
    const int tid = threadIdx.x, lane = tid & 63, wid = tid >> 6;
    const int fr = lane & 15, fq = lane >> 4;
    const int m0 = (b & 15) * 128;
    const int sel = (b >> 4) % 3, kz = b / 48;
    const int kbase = kz * 192;

    f32x4 acc[2][2];
#pragma unroll
    for (int mi = 0; mi < 2; ++mi)
#pragma unroll
        for (int ni = 0; ni < 2; ++ni) acc[mi][ni] = (f32x4){0.f,0.f,0.f,0.f};

    auto stage = [&](int buf, int k0) {
#pragma unroll
        for (int i = 0; i < 4; ++i) {     // A: 128x64 = 1024 chunks
            int cb = i * 256 + wid * 64, c = cb + lane;
            int r = c >> 3, col = ((c & 7) ^ (r & 7)) * 8;
            gload16(qkvb + (size_t)(m0 + r) * 2304 + sel*768 + k0 + col, &As[buf][cb * 8]);
        }
        {                                 // B: 32x64 = 256 chunks
            int cb = wid * 64, c = cb + lane;
            int r = c >> 3, col = ((c & 7) ^ (r & 7)) * 8;
            gload16(pT + (size_t)sel * 32*768 + (size_t)r * 768 + k0 + col, &Bs[buf][cb * 8]);
        }
    };

    stage(0, kbase);
    asm volatile("s_waitcnt vmcnt(0)" ::: "memory");
    __builtin_amdgcn_s_barrier();
    __builtin_amdgcn_sched_barrier(0);

    int cur = 0;
    for (int t = 0; t < 3; ++t) {
        if (t + 1 < 3) stage(cur ^ 1, kbase + (t + 1) * 64);
#pragma unroll
        for (int kk = 0; kk < 64; kk += 32) {
            bf16x8 a[2], bb[2];
#pragma unroll
            for (int mi = 0; mi < 2; ++mi)
                a[mi] = frag128(As[cur], wid*32 + mi*16 + fr, kk + fq*8);
#pragma unroll
            for (int ni = 0; ni < 2; ++ni)
                bb[ni] = frag128(Bs[cur], ni*16 + fr, kk + fq*8);
#pragma unroll
            for (int mi = 0; mi < 2; ++mi)
#pragma unroll
                for (int ni = 0; ni < 2; ++ni)
                    acc[mi][ni] = __builtin_amdgcn_mfma_f32_16x16x32_bf16(
                        a[mi], bb[ni], acc[mi][ni], 0, 0, 0);
        }
        asm volatile("s_waitcnt vmcnt(0)" ::: "memory");
        __builtin_amdgcn_s_barrier();
        __builtin_amdgcn_sched_barrier(0);
        cur ^= 1;
    }
#pragma unroll
    for (int mi = 0; mi < 2; ++mi)
#pragma unroll
        for (int ni = 0; ni < 2; ++ni)
#pragma unroll
            for (int v = 0; v < 4; ++v) {
                int m = m0 + wid*32 + mi*16 + fq*4 + v;
                int n = ni*16 + fr;
                pbuf[((size_t)(kz*3 + sel) * 2048 + m) * 32 + n] = acc[mi][ni][v];
            }
}

__device__ void norms_slide_body(int b, unsigned char* smem,
    const float* __restrict__ qkv,
    unsigned short* __restrict__ qhatb, unsigned short* __restrict__ khatb,
    float* __restrict__ mnear, unsigned short* __restrict__ vexptb)
{
    int tid = threadIdx.x;
    if (b < 6144) {                              // head norms
        int w = b * 4 + (tid >> 6);
        int lane = tid & 63;
        int t = w / 12, h = w - t * 12;
        float q = qkv[t*2304 + h*64 + lane];
        float k = qkv[t*2304 + 768 + h*64 + lane];
        float sq = q*q, sk = k*k;
#pragma unroll
        for (int off = 32; off; off >>= 1) { sq += __shfl_xor(sq, off); sk += __shfl_xor(sk, off); }
        float iq = 1.f / fmaxf(sqrtf(sq), 1e-12f);
        float ik = 1.f / fmaxf(sqrtf(sk), 1e-12f);
        qhatb[(size_t)t*768 + h*64 + lane] = f2b(q * iq);
        khatb[(size_t)t*768 + h*64 + lane] = f2b(k * ik);
        return;
    }
    b -= 6144;
    float (*vs)[64] = (float(*)[64])smem;        // 48 KB
    int c0 = (b % 12) * 64, t0 = (b / 12) * 64;
#pragma unroll
    for (int s = 0; s < 12; ++s) {
        int idx = tid + s * 256;
        int rr = idx >> 4, c4 = (idx & 15) * 4;
        int t = t0 - 128 + rr;
        float4 v4;
        if (t < 0) v4 = make_float4(-INFINITY, -INFINITY, -INFINITY, -INFINITY);
        else       v4 = *(const float4*)&qkv[t*2304 + 1536 + c0 + c4];
        *(float4*)&vs[rr][c4] = v4;
    }
    __syncthreads();
    int c = tid & 63, tg = tid >> 6;
    const int TG = tg * 16;
    float core = -INFINITY;
    for (int s = TG + 15; s <= TG + 128; ++s) core = fmaxf(core, vs[s][c]);
    float head[16], tail[16];
    head[15] = -INFINITY;
    float hs = -INFINITY;
#pragma unroll
    for (int u = 14; u >= 0; --u) { hs = fmaxf(hs, vs[TG + u][c]); head[u] = hs; }
    tail[0] = -INFINITY;
    float ts = -INFINITY;
#pragma unroll
    for (int u = 1; u <= 15; ++u) { ts = fmaxf(ts, vs[TG + 128 + u][c]); tail[u] = ts; }
#pragma unroll
    for (int u = 0; u < 16; ++u) {
        int tl = TG + u;
        float m = fmaxf(fmaxf(core, head[u]), tail[u]);
        float v = vs[tl + 128][c];
        int t = t0 + tl;
        mnear[(size_t)t*768 + c0 + c] = m;
        vexptb[(size_t)(c0 + c) * 2048 + t] = f2b(expf(v - m));
    }
}

__global__ __launch_bounds__(256) void lrns_pack(
    const unsigned short* __restrict__ qkvb, const unsigned short* __restrict__ pT,
    float* __restrict__ plr, const float* __restrict__ qkv,
    unsigned short* __restrict__ qhatb, unsigned short* __restrict__ khatb,
    float* __restrict__ mnear, unsigned short* __restrict__ vexptb)
{
    __shared__ unsigned char smem[49152];
    int b = blockIdx.x;
    if (b < 192) lowrank_body(b, smem, qkvb, pT, plr);
    else         norms_slide_body(b - 192, smem, qkv, qhatb, khatb, mnear, vexptb);
}

// ---------------------------------------------------------------------------
// Fused lowrank_finish + cummax (blocks 0-511: qr/kr; 512-543: Vr column).
// ---------------------------------------------------------------------------
__global__ __launch_bounds__(256) void lowrank_post(
    const float* __restrict__ pbuf,
    unsigned short* __restrict__ qrb, unsigned short* __restrict__ krb,
    unsigned short* __restrict__ evtb, float* __restrict__ ms)
{
    int b = blockIdx.x, tid = threadIdx.x;
    if (b < 512) {
        int idx = b * 256 + tid;
        int sel = idx >> 16, rem = idx & 65535;
        float s = pbuf[(size_t)(0*3 + sel)*65536 + rem]
                + pbuf[(size_t)(1*3 + sel)*65536 + rem]
                + pbuf[(size_t)(2*3 + sel)*65536 + rem]
                + pbuf[(size_t)(3*3 + sel)*65536 + rem];
        if (sel == 0) qrb[rem] = f2b(s * INV_SQRT_R);
        else          krb[rem] = f2b(s);
        return;
    }
    __shared__ float part[256];
    int r = b - 512;
    int t0 = tid * 8;
    float sv[8], v[8];
    float run = -INFINITY;
#pragma unroll
    for (int e = 0; e < 8; ++e) {
        int t = t0 + e;
        float s = pbuf[(size_t)(0*3 + 2)*65536 + t*32 + r]
                + pbuf[(size_t)(1*3 + 2)*65536 + t*32 + r]
                + pbuf[(size_t)(2*3 + 2)*65536 + t*32 + r]
                + pbuf[(size_t)(3*3 + 2)*65536 + t*32 + r];
        sv[e] = s;
        run = fmaxf(run, s);
        v[e] = run;
    }
    part[tid] = run;
    __syncthreads();
    for (int off = 1; off < 256; off <<= 1) {
        float other = (tid >= off) ? part[tid - off] : -INFINITY;
        __syncthreads();
        part[tid] = fmaxf(part[tid], other);
        __syncthreads();
    }
    float excl = (tid > 0) ? part[tid - 1] : -INFINITY;
#pragma unroll
    for (int e = 0; e < 8; ++e) {
        int t = t0 + e;
        ms[t*32 + r] = fmaxf(v[e], excl);
        evtb[(size_t)r * 2048 + t] = f2b(expf(sv[e]));
    }
}

// ---------------------------------------------------------------------------
// Packed dispatch B: seed_mfma (256 blocks, tri-masked) + near_fused (384)
// ---------------------------------------------------------------------------
__device__ void seed_body(int it, int jc, unsigned char* smem,
    const unsigned short* __restrict__ qrb, const unsigned short* __restrict__ krb,
    const unsigned short* __restrict__ evtb, float* __restrict__ partial)
{
    const int i0 = it * 128, j0 = jc * 128;
    unsigned short* Qs = (unsigned short*)smem;             // 8 KB
    unsigned short* Ks = (unsigned short*)(smem + 8192);    // 8 KB
    unsigned short* Es = (unsigned short*)(smem + 16384);   // 8 KB
    unsigned short* Ps = (unsigned short*)(smem + 24576);   // 32 KB
    const int tid = threadIdx.x, lane = tid & 63, wid = tid >> 6;
    const int fr = lane & 15, fq = lane >> 4;

#pragma unroll
    for (int s = 0; s < 2; ++s) {
        int cb = s * 256 + wid * 64;
        int c = cb + lane;
        int r = c >> 2, col = (c & 3) * 8;
        gload16(qrb + (size_t)(i0 + r) * 32 + col, &Qs[cb * 8]);
        gload16(krb + (size_t)(j0 + r) * 32 + col, &Ks[cb * 8]);
    }
#pragma unroll
    for (int s = 0; s < 2; ++s) {
        int c = s * 256 + tid;
        int rr = c >> 4, cc = c & 15;
        bf16x8 v = *(const bf16x8*)&evtb[(size_t)rr * 2048 + j0 + cc * 8];
        int byte = (rr * 256 + cc * 16) ^ ((rr & 7) << 4);
        *(bf16x8*)((char*)Es + byte) = v;
    }
    __syncthreads();

    const int wr = wid >> 1, wc = wid & 1;
    bf16x8 af[4], bk[4];
#pragma unroll
    for (int mi = 0; mi < 4; ++mi)
        af[mi] = *(const bf16x8*)&Qs[(wr*64 + mi*16 + fr)*32 + fq*8];
#pragma unroll
    for (int ni = 0; ni < 4; ++ni)
        bk[ni] = *(const bf16x8*)&Ks[(wc*64 + ni*16 + fr)*32 + fq*8];
#pragma unroll
    for (int mi = 0; mi < 4; ++mi)
#pragma unroll
        for (int ni = 0; ni < 4; ++ni) {
            f32x4 s4 = __builtin_amdgcn_mfma_f32_16x16x32_bf16(
                af[mi], bk[ni], (f32x4){0.f,0.f,0.f,0.f}, 0, 0, 0);
#pragma unroll
            for (int v = 0; v < 4; ++v) {
                int row = wr*64 + mi*16 + fq*4 + v;
                int col = wc*64 + ni*16 + fr;
                float a = 0.f;
                if (j0 + col <= i0 + row) {
                    float s = s4[v];
                    a = 1.f / (1.f + expf(-(s*s + B_SCALAR)));
                }
                int byte = (row * 256 + col * 2) ^ ((row & 7) << 4);
                *(unsigned short*)((char*)Ps + byte) = f2b(a);
            }
        }
    __syncthreads();

    f32x4 yacc[2][2];
#pragma unroll
    for (int mi = 0; mi < 2; ++mi)
#pragma unroll
        for (int nf = 0; nf < 2; ++nf) yacc[mi][nf] = (f32x4){0.f,0.f,0.f,0.f};
#pragma unroll
    for (int ks = 0; ks < 4; ++ks) {
        bf16x8 pa[2], eb[2];
#pragma unroll
        for (int mi = 0; mi < 2; ++mi) {
            int row = wid*32 + mi*16 + fr;
            int byte = (row * 256 + ks * 64 + fq * 16) ^ ((row & 7) << 4);
            pa[mi] = *(const bf16x8*)((const char*)Ps + byte);
        }
#pragma unroll
        for (int nf = 0; nf < 2; ++nf) {
            int rrow = nf*16 + fr;
            int byte = (rrow * 256 + ks * 64 + fq * 16) ^ ((rrow & 7) << 4);
            eb[nf] = *(const bf16x8*)((const char*)Es + byte);
        }
#pragma unroll
        for (int mi = 0; mi < 2; ++mi)
#pragma unroll
            for (int nf = 0; nf < 2; ++nf)
                yacc[mi][nf] = __builtin_amdgcn_mfma_f32_16x16x32_bf16(
                    pa[mi], eb[nf], yacc[mi][nf], 0, 0, 0);
    }
    float* pout = partial + ((size_t)(it*16 + jc) * 128) * 32;
#pragma unroll
    for (int mi = 0; mi < 2; ++mi)
#pragma unroll
        for (int nf = 0; nf < 2; ++nf)
#pragma unroll
            for (int v = 0; v < 4; ++v) {
                int row = wid*32 + mi*16 + fq*4 + v;
                int col = nf*16 + fr;
                pout[row*32 + col] = yacc[mi][nf][v];
            }
}

__device__ void near_body(int it, int hh, unsigned char* smem,
    const unsigned short* __restrict__ qhatb, const unsigned short* __restrict__ khatb,
    const unsigned short* __restrict__ vexptb, const float* __restrict__ mnear,
    const float* __restrict__ gu, const float* __restrict__ gb,
    float* __restrict__ hn, unsigned short* __restrict__ htlb)
{
    unsigned short* Qs  = (unsigned short*)smem;             // 8 KB
    unsigned short* KPs = (unsigned short*)(smem + 8192);    // 24 KB
    unsigned short* Vst = (unsigned short*)(smem + 32768);   // 24 KB
    const int i0 = it * 64;
    const int tid = threadIdx.x, lane = tid & 63, wid = tid >> 6;
    const int fr = lane & 15, fq = lane >> 4;

#pragma unroll
    for (int i = 0; i < 2; ++i) {
        int cb = i * 256 + wid * 64, c = cb + lane;
        int r = c >> 3, col = ((c & 7) ^ (r & 7)) * 8;
        gload16(qhatb + (size_t)(i0 + r) * 768 + hh*64 + col, &Qs[cb * 8]);
    }
#pragma unroll
    for (int i = 0; i < 6; ++i) {
        int cb = i * 256 + wid * 64, c = cb + lane;
        int r = c >> 3, col = ((c & 7) ^ (r & 7)) * 8;
        int j = i0 - 128 + r; if (j < 0) j = 0;
        gload16(khatb + (size_t)j * 768 + hh*64 + col, &KPs[cb * 8]);
    }
#pragma unroll
    for (int i = 0; i < 6; ++i) {
        int cb = i * 256 + wid * 64, c = cb + lane;
        int d = c / 24, cc = c - d * 24;
        int ccp = (cc & 24) | ((cc & 7) ^ (d & 7));
        int t = i0 - 128 + ccp * 8; if (t < 0) t = 0;
        gload16(vexptb + (size_t)(hh*64 + d) * 2048 + t, &Vst[cb * 8]);
    }
    __syncthreads();

    f32x4 sacc[4][3];
#pragma unroll
    for (int mi = 0; mi < 4; ++mi)
#pragma unroll
        for (int ni = 0; ni < 3; ++ni) sacc[mi][ni] = (f32x4){0.f,0.f,0.f,0.f};
#pragma unroll
    for (int kt = 0; kt < 2; ++kt) {
        int kk = kt * 32;
        bf16x8 qa[4], kb[3];
#pragma unroll
        for (int mi = 0; mi < 4; ++mi)
            qa[mi] = frag128(Qs, mi*16 + fr, kk + fq*8);
#pragma unroll
        for (int ni = 0; ni < 3; ++ni)
            kb[ni] = frag128(KPs, wid*48 + ni*16 + fr, kk + fq*8);
#pragma unroll
        for (int mi = 0; mi < 4; ++mi)
#pragma unroll
            for (int ni = 0; ni < 3; ++ni)
                sacc[mi][ni] = __builtin_amdgcn_mfma_f32_16x16x32_bf16(
                    qa[mi], kb[ni], sacc[mi][ni], 0, 0, 0);
    }
    __syncthreads();

#pragma unroll
    for (int mi = 0; mi < 4; ++mi)
#pragma unroll
        for (int ni = 0; ni < 3; ++ni)
#pragma unroll
            for (int v = 0; v < 4; ++v) {
                int il = mi*16 + fq*4 + v;
                int jl = wid*48 + ni*16 + fr;
                float s = sacc[mi][ni][v];
                float a = 0.f;
                if (jl >= il && jl <= il + 128 && (i0 - 128 + jl) >= 0)
                    a = 1.f / (1.f + expf(-(s*s*INV_TAU + B_SCALAR)));
                int byte = (il * 384 + jl * 2) ^ ((il & 7) << 4);
                *(unsigned short*)((char*)KPs + byte) = f2b(a);
            }
    __syncthreads();

    f32x4 yacc[4];
#pragma unroll
    for (int nf = 0; nf < 4; ++nf) yacc[nf] = (f32x4){0.f,0.f,0.f,0.f};
#pragma unroll
    for (int ks = 0; ks < 6; ++ks) {
        int kk = ks * 32;
        bf16x8 pa = frag384(KPs, wid*16 + fr, kk + fq*8);
        bf16x8 vb[4];
#pragma unroll
        for (int nf = 0; nf < 4; ++nf)
            vb[nf] = frag384(Vst, nf*16 + fr, kk + fq*8);
#pragma unroll
        for (int nf = 0; nf < 4; ++nf)
            yacc[nf] = __builtin_amdgcn_mfma_f32_16x16x32_bf16(pa, vb[nf], yacc[nf], 0, 0, 0);
    }

    float hv[4][4];
    float sp[4] = {0.f, 0.f, 0.f, 0.f};
#pragma unroll
    for (int nf = 0; nf < 4; ++nf) {
        int d = nf*16 + fr;
        float guv = gu[hh*64 + d];
#pragma unroll
        for (int v = 0; v < 4; ++v) {
            int row = wid*16 + fq*4 + v;
            float y = yacc[nf][v];
            float h = logf(fmaxf(y, 1e-30f)) + mnear[(size_t)(i0 + row)*768 + hh*64 + d];
            hv[nf][v] = h;
            sp[v] = fmaf(h, guv, sp[v]);
        }
    }
#pragma unroll
    for (int off = 1; off < 16; off <<= 1) {
#pragma unroll
        for (int v = 0; v < 4; ++v) sp[v] += __shfl_xor(sp[v], off);
    }
    float gbh = gb[hh];
#pragma unroll
    for (int v = 0; v < 4; ++v) sp[v] = 1.f / (1.f + expf(-(sp[v] + gbh)));
#pragma unroll
    for (int nf = 0; nf < 4; ++nf)
#pragma unroll
        for (int v = 0; v < 4; ++v) {
            int row = wid*16 + fq*4 + v;
            int d = nf*16 + fr;
            size_t idx = (size_t)(i0 + row)*768 + hh*64 + d;
            float htl = hv[nf][v] * sp[v];
            hn[idx] = htl;
            htlb[idx] = f2b(htl);
        }
}

__global__ __launch_bounds__(256) void seednear_pack(
    const unsigned short* __restrict__ qrb, const unsigned short* __restrict__ krb,
    const unsigned short* __restrict__ evtb, float* __restrict__ partial,
    const unsigned short* __restrict__ qhatb, const unsigned short* __restrict__ khatb,
    const unsigned short* __restrict__ vexptb, const float* __restrict__ mnear,
    const float* __restrict__ gu, const float* __restrict__ gb,
    float* __restrict__ hn, unsigned short* __restrict__ htlb)
{
    __shared__ unsigned char smem[57344];
    int b = blockIdx.x;
    if (b < 256) {
        int it = b >> 4, jc = b & 15;
        if (jc > it) return;
        seed_body(it, jc, smem, qrb, krb, evtb, partial);
    } else {
        int idx = b - 256;
        near_body(idx & 31, idx >> 5, smem, qhatb, khatb, vexptb, mnear,
                  gu, gb, hn, htlb);
    }
}

// ---------------------------------------------------------------------------
// Fused: reduce seed partials + LASER log + H0 = Lr @ up_w (+ bf16 copy).
// ---------------------------------------------------------------------------
__global__ __launch_bounds__(256) void seed_up(
    const float* __restrict__ partial, const float* __restrict__ ms,
    const float* __restrict__ up, float* __restrict__ h0,
    unsigned short* __restrict__ h0b)
{
    __shared__ float ls[32];
    int t = blockIdx.x, tid = threadIdx.x;
    if (tid < 32) {
        int r = tid;
        int it = t >> 7, row = t & 127;
        float y = 0.f;
        for (int jjc = 0; jjc <= it; ++jjc)
            y += partial[(((size_t)(it*16 + jjc) * 128) + row) * 32 + r];
        float m = ms[t*32 + r];
        ls[r] = logf(fmaxf(y * expf(-m), 1e-30f)) + m;
    }
    __syncthreads();
    for (int c = tid; c < 768; c += 256) {
        float acc = 0.f;
#pragma unroll
        for (int rr = 0; rr < 32; ++rr) acc = fmaf(ls[rr], up[rr*768 + c], acc);
        h0[(size_t)t*768 + c] = acc;
        h0b[(size_t)t*768 + c] = f2b(acc);
    }
}

// ---------------------------------------------------------------------------
extern "C" void kernel_launch(void* const* d_in, const int* in_sizes, int n_in,
                              void* d_out, int out_size, void* d_ws, size_t ws_size,
                              hipStream_t stream)
{
    const float* x  = (const float*)d_in[0];
    const float* wq = (const float*)d_in[1];  const float* bq = (const float*)d_in[2];
    const float* wk = (const float*)d_in[3];  const float* bk = (const float*)d_in[4];
    const float* wv = (const float*)d_in[5];  const float* bv = (const float*)d_in[6];
    const float* wo = (const float*)d_in[7];  const float* bo = (const float*)d_in[8];
    const float* pq = (const float*)d_in[9];  const float* pk = (const float*)d_in[10];
    const float* pv = (const float*)d_in[11];
    const float* up = (const float*)d_in[12];
    const float* gu = (const float*)d_in[13]; const float* gb = (const float*)d_in[14];
    const float* wz = (const float*)d_in[15]; const float* bz = (const float*)d_in[16];
    float* out = (float*)d_out;

    float* w = (float*)d_ws;
    float* qkv  = w; w += 2048*2304;
    float* ms   = w; w += 2048*32;
    float* h0   = w; w += 2048*768;
    float* mnear= w; w += 2048*768;
    float* hn   = w; w += 2048*768;          // Htilde after near_fused
    float* partial = w; w += 16*16*128*32;   // seed partials
    float* pgemm = w; w += 4*2048*768;       // Wz split-K partials
    float* plr   = w; w += 4*3*2048*32;      // lowrank split-K partials
    float* bqkv = w; w += 2304;
    unsigned short* xb     = (unsigned short*)w; w += 2048*768/2;
    unsigned short* qkvb   = (unsigned short*)w; w += 2048*2304/2;
    unsigned short* wqkvT  = (unsigned short*)w; w += 2304*768/2;
    unsigned short* wzT    = (unsigned short*)w; w += 768*3072/2;
    unsigned short* woT    = (unsigned short*)w; w += 768*768/2;
    unsigned short* pT     = (unsigned short*)w; w += 3*32*768/2;
    unsigned short* h0b    = (unsigned short*)w; w += 2048*768/2;
    unsigned short* htlb   = (unsigned short*)w; w += 2048*768/2;
    unsigned short* houtb  = (unsigned short*)w; w += 2048*768/2;
    unsigned short* qrb    = (unsigned short*)w; w += 2048*32/2;
    unsigned short* krb    = (unsigned short*)w; w += 2048*32/2;
    unsigned short* evtb   = (unsigned short*)w; w += 32*2048/2;
    unsigned short* qhatb  = (unsigned short*)w; w += 2048*768/2;
    unsigned short* khatb  = (unsigned short*)w; w += 2048*768/2;
    unsigned short* vexptb = (unsigned short*)w; w += 768*2048/2;

    // 1) prep (single mega-dispatch)
    prep_all<<<6225, 256, 0, stream>>>(x, xb, wq, wk, wv, wqkvT, wz, wzT,
                                       wo, woT, pq, pk, pv, pT, bq, bk, bv, bqkv);

    // 2) QKV projections (fp32 + bf16 copy), XCD-swizzled
    gemm_mfma<0,1><<<dim3(18,32,1), 256, 0, stream>>>(xb, nullptr, nullptr,
        wqkvT, bqkv, qkv, qkvb, nullptr, 768, 2304);

    // 3) lowrank GEMM + head-norms + sliding-max (packed)
    lrns_pack<<<6720, 256, 0, stream>>>(qkvb, pT, plr, qkv, qhatb, khatb, mnear, vexptb);

    // 4) lowrank combine + cummax
    lowrank_post<<<544, 256, 0, stream>>>(plr, qrb, krb, evtb, ms);

    // 5) seed attention + near-field attention (packed)
    seednear_pack<<<640, 256, 0, stream>>>(qrb, krb, evtb, partial,
        qhatb, khatb, vexptb, mnear, gu, gb, hn, htlb);

    // 6) seed reduce + H0 up-projection
    seed_up<<<2048, 256, 0, stream>>>(partial, ms, up, h0, h0b);

    // 7) Wz GEMM (split-K=4, inline h0*htl piece), XCD-swizzled
    gemm_mfma<1,4><<<dim3(6,32,4), 256, 0, stream>>>(xb, h0b, htlb,
        wzT, nullptr, nullptr, nullptr, pgemm, 3072, 768);

    // 8) Wz combine + GRU blend
    wz_combine<<<1536, 256, 0, stream>>>(pgemm, bz, h0, hn, houtb);

    // 9) Wo GEMM (KZ=1, bias fused, direct out), XCD-swizzled
    gemm_mfma<2,1><<<dim3(6,32,1), 256, 0, stream>>>(houtb, nullptr, nullptr,
        woT, bo, out, nullptr, nullptr, 768, 768);
}

// Round 12
// 145.646 us; speedup vs baseline: 1.0252x; 1.0226x over previous
//
#include <hip/hip_runtime.h>
#include <math.h>

// Problem constants (fixed: B=1, T=2048, C=768, H=12, D=64, R=32, K0=128)
static constexpr float B_SCALAR    = -7.6246189861593985f;   // -log(2048)
static constexpr float INV_TAU     = 2.8571428571428571f;    // 1/0.35
static constexpr float INV_SQRT_R  = 0.17677669529663687f;   // 1/sqrt(32)

typedef __attribute__((ext_vector_type(8))) short bf16x8;
typedef __attribute__((ext_vector_type(4))) float f32x4;

__device__ __forceinline__ unsigned short f2b(float f) {
    union { float f; unsigned int u; } v; v.f = f;
    unsigned int r = v.u + 0x7fffu + ((v.u >> 16) & 1u);
    return (unsigned short)(r >> 16);
}
__device__ __forceinline__ float b2f(unsigned short u) {
    union { unsigned int i; float f; } v; v.i = ((unsigned int)u) << 16; return v.f;
}

typedef const __attribute__((address_space(1))) unsigned int* gp1_t;
typedef __attribute__((address_space(3))) unsigned int* lp3_t;
__device__ __forceinline__ void gload16(const unsigned short* g, unsigned short* l) {
    __builtin_amdgcn_global_load_lds((gp1_t)g, (lp3_t)l, 16, 0, 0);
}

// XOR-swizzled bf16x8 read from a row-major LDS tile with 128B rows
__device__ __forceinline__ bf16x8 frag128(const unsigned short* base, int row, int elem) {
    int byte = (row * 128 + elem * 2) ^ ((row & 7) << 4);
    return *(const bf16x8*)((const char*)base + byte);
}
// same for 384B rows (192 bf16 per row)
__device__ __forceinline__ bf16x8 frag384(const unsigned short* base, int row, int elem) {
    int byte = (row * 384 + elem * 2) ^ ((row & 7) << 4);
    return *(const bf16x8*)((const char*)base + byte);
}

// ---------------------------------------------------------------------------
// bf16 MFMA GEMM, 64x128 tile, BK=64, double-buffered 2-phase prefetch,
// XOR-swizzled LDS, XCD-aware block swizzle (grid x*y %8==0).
// MODE 0: QKV (KZ=1, bf16 out only, bias)
// MODE 1: Wz, A piecewise xb|h0b|htlb|inline(h0b*htlb), split-K -> pbuf
// MODE 2: Wo (split-K -> pbuf)
// ---------------------------------------------------------------------------
template<int MODE, int KZ>
__global__ __launch_bounds__(256) void gemm_mfma(
    const unsigned short* __restrict__ A0, const unsigned short* __restrict__ A1,
    const unsigned short* __restrict__ A2,
    const unsigned short* __restrict__ Bt, const float* __restrict__ bias,
    float* __restrict__ outf, unsigned short* __restrict__ outb,
    float* __restrict__ pbuf, int K, int ldo)
{
    __shared__ unsigned short As[2][64*64];    // 16 KB
    __shared__ unsigned short Bs[2][128*64];   // 32 KB
    const int tid = threadIdx.x;
    const int lane = tid & 63, wid = tid >> 6;
    const int wr = wid >> 1, wc = wid & 1;
    const int fr = lane & 15, fq = lane >> 4;
    const int lin = blockIdx.y * gridDim.x + blockIdx.x;
    const int chunk = (gridDim.x * gridDim.y) >> 3;
    const int sw = (lin & 7) * chunk + (lin >> 3);
    const int n0 = (sw / gridDim.y) * 128, m0 = (sw % gridDim.y) * 64;
    const int kz = blockIdx.z;
    const int kslice = K / KZ;
    const int kbase = kz * kslice;
    const int nt = kslice / 64;

    f32x4 acc[2][4];
#pragma unroll
    for (int mi = 0; mi < 2; ++mi)
#pragma unroll
        for (int ni = 0; ni < 4; ++ni) acc[mi][ni] = (f32x4){0.f, 0.f, 0.f, 0.f};

    auto stage = [&](int buf, int k0) {
        if (MODE == 1 && k0 >= 2304) {
            int k0l = k0 - 2304;
#pragma unroll
            for (int i = 0; i < 2; ++i) {
                int cb = i * 256 + wid * 64, c = cb + lane;
                int r = c >> 3, col = ((c & 7) ^ (r & 7)) * 8;
                bf16x8 a8 = *(const bf16x8*)&A1[(size_t)(m0 + r) * 768 + k0l + col];
                bf16x8 b8 = *(const bf16x8*)&A2[(size_t)(m0 + r) * 768 + k0l + col];
                bf16x8 p8;
#pragma unroll
                for (int e = 0; e < 8; ++e)
                    p8[e] = (short)f2b(b2f((unsigned short)a8[e]) * b2f((unsigned short)b8[e]));
                *(bf16x8*)&As[buf][(size_t)c * 8] = p8;
            }
        } else {
            const unsigned short* Ap;
            int k0l, ldA;
            if (MODE == 1) {
                int p = k0 / 768;
                Ap = (p == 0) ? A0 : (p == 1) ? A1 : A2;
                k0l = k0 - p * 768; ldA = 768;
            } else { Ap = A0; k0l = k0; ldA = K; }
#pragma unroll
            for (int i = 0; i < 2; ++i) {
                int cb = i * 256 + wid * 64, c = cb + lane;
                int r = c >> 3;
                int col = ((c & 7) ^ (r & 7)) * 8;
                gload16(Ap + (size_t)(m0 + r) * ldA + k0l + col, &As[buf][cb * 8]);
            }
        }
#pragma unroll
        for (int i = 0; i < 4; ++i) {
            int cb = i * 256 + wid * 64, c = cb + lane;
            int r = c >> 3;
            int col = ((c & 7) ^ (r & 7)) * 8;
            gload16(Bt + (size_t)(n0 + r) * K + k0 + col, &Bs[buf][cb * 8]);
        }
    };
    auto wait_all = [&]() {
        if constexpr (MODE == 1)
            asm volatile("s_waitcnt vmcnt(0) lgkmcnt(0)" ::: "memory");
        else
            asm volatile("s_waitcnt vmcnt(0)" ::: "memory");
    };

    stage(0, kbase);
    wait_all();
    __builtin_amdgcn_s_barrier();
    __builtin_amdgcn_sched_barrier(0);

    int cur = 0;
    for (int t = 0; t < nt; ++t) {
        if (t + 1 < nt) stage(cur ^ 1, kbase + (t + 1) * 64);
#pragma unroll
        for (int kk = 0; kk < 64; kk += 32) {
            bf16x8 af[2], bfr[4];
#pragma unroll
            for (int mi = 0; mi < 2; ++mi)
                af[mi] = frag128(As[cur], wr*32 + mi*16 + fr, kk + fq*8);
#pragma unroll
            for (int ni = 0; ni < 4; ++ni)
                bfr[ni] = frag128(Bs[cur], wc*64 + ni*16 + fr, kk + fq*8);
#pragma unroll
            for (int mi = 0; mi < 2; ++mi)
#pragma unroll
                for (int ni = 0; ni < 4; ++ni)
                    acc[mi][ni] = __builtin_amdgcn_mfma_f32_16x16x32_bf16(
                        af[mi], bfr[ni], acc[mi][ni], 0, 0, 0);
        }
        wait_all();
        __builtin_amdgcn_s_barrier();
        __builtin_amdgcn_sched_barrier(0);
        cur ^= 1;
    }
#pragma unroll
    for (int mi = 0; mi < 2; ++mi)
#pragma unroll
        for (int ni = 0; ni < 4; ++ni)
#pragma unroll
            for (int v = 0; v < 4; ++v) {
                int m = m0 + wr*32 + mi*16 + fq*4 + v;
                int n = n0 + wc*64 + ni*16 + fr;
                float val = acc[mi][ni][v];
                if (KZ > 1) {
                    pbuf[((size_t)kz * 2048 + m) * 768 + n] = val;
                } else if (MODE == 0) {
                    outb[(size_t)m * ldo + n] = f2b(val + bias[n]);
                } else {
                    outf[(size_t)m * ldo + n] = val + bias[n];
                }
            }
}

// ---------------------------------------------------------------------------
// Split-K combines
// ---------------------------------------------------------------------------
__global__ __launch_bounds__(256) void wz_combine(
    const float* __restrict__ pbuf, const float* __restrict__ bz,
    const float* __restrict__ h0, const float* __restrict__ htl,
    unsigned short* __restrict__ outb)
{
    int i = blockIdx.x * 256 + threadIdx.x;
    if (i >= 2048*768/4) return;
    float4 s = *(const float4*)&pbuf[i*4];
    float4 p1 = *(const float4*)&pbuf[1536*1024 + i*4];
    float4 p2 = *(const float4*)&pbuf[2*1536*1024 + i*4];
    float4 p3 = *(const float4*)&pbuf[3*1536*1024 + i*4];
    s.x += p1.x + p2.x + p3.x; s.y += p1.y + p2.y + p3.y;
    s.z += p1.z + p2.z + p3.z; s.w += p1.w + p2.w + p3.w;
    float4 b = *(const float4*)&bz[(i % 192) * 4];
    float4 a = *(const float4*)&h0[i*4];
    float4 t = *(const float4*)&htl[i*4];
    float z0 = 1.f/(1.f+expf(-(s.x+b.x))), z1 = 1.f/(1.f+expf(-(s.y+b.y)));
    float z2 = 1.f/(1.f+expf(-(s.z+b.z))), z3 = 1.f/(1.f+expf(-(s.w+b.w)));
    outb[i*4+0] = f2b((1.f-z0)*a.x + z0*t.x);
    outb[i*4+1] = f2b((1.f-z1)*a.y + z1*t.y);
    outb[i*4+2] = f2b((1.f-z2)*a.z + z2*t.z);
    outb[i*4+3] = f2b((1.f-z3)*a.w + z3*t.w);
}

__global__ __launch_bounds__(256) void wo_combine(
    const float* __restrict__ pbuf, const float* __restrict__ bo,
    float* __restrict__ out)
{
    int i = blockIdx.x * 256 + threadIdx.x;
    if (i >= 2048*768/4) return;
    float4 s = *(const float4*)&pbuf[i*4];
    float4 p1 = *(const float4*)&pbuf[1536*1024 + i*4];
    float4 b = *(const float4*)&bo[(i % 192) * 4];
    float4 o;
    o.x = s.x + p1.x + b.x; o.y = s.y + p1.y + b.y;
    o.z = s.z + p1.z + b.z; o.w = s.w + p1.w + b.w;
    *(float4*)&out[i*4] = o;
}

// ---------------------------------------------------------------------------
// Mega-prep: x->bf16 cast, all weight transposes (fp32->bf16), bias concat.
// ---------------------------------------------------------------------------
__global__ __launch_bounds__(256) void prep_all(
    const float* __restrict__ x, unsigned short* __restrict__ xb,
    const float* __restrict__ wq, const float* __restrict__ wk,
    const float* __restrict__ wv, unsigned short* __restrict__ wqkvT,
    const float* __restrict__ wz, unsigned short* __restrict__ wzT,
    const float* __restrict__ wo, unsigned short* __restrict__ woT,
    const float* __restrict__ pq, const float* __restrict__ pk,
    const float* __restrict__ pv, unsigned short* __restrict__ pT,
    const float* __restrict__ bq, const float* __restrict__ bk,
    const float* __restrict__ bv, float* __restrict__ bqkv)
{
    __shared__ float tile[32][33];
    int b = blockIdx.x;
    if (b < 1536) {                       // cvt x -> xb
        int i = b * 256 + threadIdx.x;
        float4 v = *(const float4*)&x[i * 4];
        xb[i*4+0] = f2b(v.x); xb[i*4+1] = f2b(v.y);
        xb[i*4+2] = f2b(v.z); xb[i*4+3] = f2b(v.w);
        return;
    }
    b -= 1536;
    const float* src; unsigned short* dst; int K, N, tb;
    if (b < 1728) {                       // wq/wk/wv (576 each)
        int sel = b / 576;
        src = (sel == 0) ? wq : (sel == 1) ? wk : wv;
        dst = wqkvT + (size_t)sel * 768 * 768;
        K = 768; N = 768; tb = b - sel * 576;
    } else if (b < 4032) {                // wz (2304)
        src = wz; dst = wzT; K = 3072; N = 768; tb = b - 1728;
    } else if (b < 4608) {                // wo (576)
        src = wo; dst = woT; K = 768; N = 768; tb = b - 4032;
    } else if (b < 4680) {                // pq/pk/pv (24 each)
        int sel = (b - 4608) / 24;
        src = (sel == 0) ? pq : (sel == 1) ? pk : pv;
        dst = pT + (size_t)sel * 32 * 768;
        K = 768; N = 32; tb = (b - 4608) % 24;
    } else {                              // concat_bias (9)
        int n = (b - 4680) * 256 + threadIdx.x;
        if (n < 2304)
            bqkv[n] = (n < 768) ? bq[n] : (n < 1536) ? bk[n - 768] : bv[n - 1536];
        return;
    }
    int kt = K / 32;
    int kb = (tb % kt) * 32, nb = (tb / kt) * 32;
    int tx = threadIdx.x & 31, ty = threadIdx.x >> 5;
#pragma unroll
    for (int s = 0; s < 32; s += 8)
        tile[ty + s][tx] = src[(size_t)(kb + ty + s) * N + nb + tx];
    __syncthreads();
#pragma unroll
    for (int s = 0; s < 32; s += 8)
        dst[(size_t)(nb + ty + s) * K + kb + tx] = f2b(tile[tx][ty + s]);
}

// ---------------------------------------------------------------------------
// Packed dispatch A: lowrank_mfma (192 blocks) + norms/slide (6528 blocks),
// all reading bf16 qkvb.
// ---------------------------------------------------------------------------
__device__ void lowrank_body(int b, unsigned char* smem,
    const unsigned short* __restrict__ qkvb, const unsigned short* __restrict__ pT,
    float* __restrict__ pbuf)
{
    unsigned short (*As)[128*64] = (unsigned short(*)[128*64])smem;          // 32 KB
    unsigned short (*Bs)[32*64]  = (unsigned short(*)[32*64])(smem + 32768); // 8 KB
    const int tid = threadIdx.x, lane = tid & 63, wid = tid >> 6;
    const int fr = lane & 15, fq = lane >> 4;
    const int m0 = (b & 15) * 128;
    const int sel = (b >> 4) % 3, kz = b / 48;
    const int kbase = kz * 192;

    f32x4 acc[2][2];
#pragma unroll
    for (int mi = 0; mi < 2; ++mi)
#pragma unroll
        for (int ni = 0; ni < 2; ++ni) acc[mi][ni] = (f32x4){0.f,0.f,0.f,0.f};

    auto stage = [&](int buf, int k0) {
#pragma unroll
        for (int i = 0; i < 4; ++i) {
            int cb = i * 256 + wid * 64, c = cb + lane;
            int r = c >> 3, col = ((c & 7) ^ (r & 7)) * 8;
            gload16(qkvb + (size_t)(m0 + r) * 2304 + sel*768 + k0 + col, &As[buf][cb * 8]);
        }
        {
            int cb = wid * 64, c = cb + lane;
            int r = c >> 3, col = ((c & 7) ^ (r & 7)) * 8;
            gload16(pT + (size_t)sel * 32*768 + (size_t)r * 768 + k0 + col, &Bs[buf][cb * 8]);
        }
    };

    stage(0, kbase);
    asm volatile("s_waitcnt vmcnt(0)" ::: "memory");
    __builtin_amdgcn_s_barrier();
    __builtin_amdgcn_sched_barrier(0);

    int cur = 0;
    for (int t = 0; t < 3; ++t) {
        if (t + 1 < 3) stage(cur ^ 1, kbase + (t + 1) * 64);
#pragma unroll
        for (int kk = 0; kk < 64; kk += 32) {
            bf16x8 a[2], bb[2];
#pragma unroll
            for (int mi = 0; mi < 2; ++mi)
                a[mi] = frag128(As[cur], wid*32 + mi*16 + fr, kk + fq*8);
#pragma unroll
            for (int ni = 0; ni < 2; ++ni)
                bb[ni] = frag128(Bs[cur], ni*16 + fr, kk + fq*8);
#pragma unroll
            for (int mi = 0; mi < 2; ++mi)
#pragma unroll
                for (int ni = 0; ni < 2; ++ni)
                    acc[mi][ni] = __builtin_amdgcn_mfma_f32_16x16x32_bf16(
                        a[mi], bb[ni], acc[mi][ni], 0, 0, 0);
        }
        asm volatile("s_waitcnt vmcnt(0)" ::: "memory");
        __builtin_amdgcn_s_barrier();
        __builtin_amdgcn_sched_barrier(0);
        cur ^= 1;
    }
#pragma unroll
    for (int mi = 0; mi < 2; ++mi)
#pragma unroll
        for (int ni = 0; ni < 2; ++ni)
#pragma unroll
            for (int v = 0; v < 4; ++v) {
                int m = m0 + wid*32 + mi*16 + fq*4 + v;
                int n = ni*16 + fr;
                pbuf[((size_t)(kz*3 + sel) * 2048 + m) * 32 + n] = acc[mi][ni][v];
            }
}

__device__ void norms_slide_body(int b, unsigned char* smem,
    const unsigned short* __restrict__ qkvb,
    unsigned short* __restrict__ qhatb, unsigned short* __restrict__ khatb,
    float* __restrict__ mnear, unsigned short* __restrict__ vexptb)
{
    int tid = threadIdx.x;
    if (b < 6144) {                              // head norms (from bf16 qkvb)
        int w = b * 4 + (tid >> 6);
        int lane = tid & 63;
        int t = w / 12, h = w - t * 12;
        float q = b2f(qkvb[(size_t)t*2304 + h*64 + lane]);
        float k = b2f(qkvb[(size_t)t*2304 + 768 + h*64 + lane]);
        float sq = q*q, sk = k*k;
#pragma unroll
        for (int off = 32; off; off >>= 1) { sq += __shfl_xor(sq, off); sk += __shfl_xor(sk, off); }
        float iq = 1.f / fmaxf(sqrtf(sq), 1e-12f);
        float ik = 1.f / fmaxf(sqrtf(sk), 1e-12f);
        qhatb[(size_t)t*768 + h*64 + lane] = f2b(q * iq);
        khatb[(size_t)t*768 + h*64 + lane] = f2b(k * ik);
        return;
    }
    b -= 6144;
    float (*vs)[64] = (float(*)[64])smem;        // 48 KB
    int c0 = (b % 12) * 64, t0 = (b / 12) * 64;
#pragma unroll
    for (int s = 0; s < 6; ++s) {                // 192 rows x 8 col-groups
        int idx = tid + s * 256;
        int rr = idx >> 3, c8 = (idx & 7) * 8;
        int t = t0 - 128 + rr;
        if (t < 0) {
#pragma unroll
            for (int e = 0; e < 8; ++e) vs[rr][c8 + e] = -INFINITY;
        } else {
            bf16x8 v8 = *(const bf16x8*)&qkvb[(size_t)t*2304 + 1536 + c0 + c8];
#pragma unroll
            for (int e = 0; e < 8; ++e) vs[rr][c8 + e] = b2f((unsigned short)v8[e]);
        }
    }
    __syncthreads();
    int c = tid & 63, tg = tid >> 6;
    const int TG = tg * 16;
    float core = -INFINITY;
    for (int s = TG + 15; s <= TG + 128; ++s) core = fmaxf(core, vs[s][c]);
    float head[16], tail[16];
    head[15] = -INFINITY;
    float hs = -INFINITY;
#pragma unroll
    for (int u = 14; u >= 0; --u) { hs = fmaxf(hs, vs[TG + u][c]); head[u] = hs; }
    tail[0] = -INFINITY;
    float ts = -INFINITY;
#pragma unroll
    for (int u = 1; u <= 15; ++u) { ts = fmaxf(ts, vs[TG + 128 + u][c]); tail[u] = ts; }
#pragma unroll
    for (int u = 0; u < 16; ++u) {
        int tl = TG + u;
        float m = fmaxf(fmaxf(core, head[u]), tail[u]);
        float v = vs[tl + 128][c];
        int t = t0 + tl;
        mnear[(size_t)t*768 + c0 + c] = m;
        vexptb[(size_t)(c0 + c) * 2048 + t] = f2b(expf(v - m));
    }
}

__global__ __launch_bounds__(256) void lrns_pack(
    const unsigned short* __restrict__ qkvb, const unsigned short* __restrict__ pT,
    float* __restrict__ plr,
    unsigned short* __restrict__ qhatb, unsigned short* __restrict__ khatb,
    float* __restrict__ mnear, unsigned short* __restrict__ vexptb)
{
    __shared__ unsigned char smem[49152];
    int b = blockIdx.x;
    if (b < 192) lowrank_body(b, smem, qkvb, pT, plr);
    else         norms_slide_body(b - 192, smem, qkvb, qhatb, khatb, mnear, vexptb);
}

// ---------------------------------------------------------------------------
// Fused lowrank_finish + cummax (blocks 0-511: qr/kr; 512-543: Vr column).
// ---------------------------------------------------------------------------
__global__ __launch_bounds__(256) void lowrank_post(
    const float* __restrict__ pbuf,
    unsigned short* __restrict__ qrb, unsigned short* __restrict__ krb,
    unsigned short* __restrict__ evtb, float* __restrict__ ms)
{
    int b = blockIdx.x, tid = threadIdx.x;
    if (b < 512) {
        int idx = b * 256 + tid;
        int sel = idx >> 16, rem = idx & 65535;
        float s = pbuf[(size_t)(0*3 + sel)*65536 + rem]
                + pbuf[(size_t)(1*3 + sel)*65536 + rem]
                + pbuf[(size_t)(2*3 + sel)*65536 + rem]
                + pbuf[(size_t)(3*3 + sel)*65536 + rem];
        if (sel == 0) qrb[rem] = f2b(s * INV_SQRT_R);
        else          krb[rem] = f2b(s);
        return;
    }
    __shared__ float part[256];
    int r = b - 512;
    int t0 = tid * 8;
    float sv[8], v[8];
    float run = -INFINITY;
#pragma unroll
    for (int e = 0; e < 8; ++e) {
        int t = t0 + e;
        float s = pbuf[(size_t)(0*3 + 2)*65536 + t*32 + r]
                + pbuf[(size_t)(1*3 + 2)*65536 + t*32 + r]
                + pbuf[(size_t)(2*3 + 2)*65536 + t*32 + r]
                + pbuf[(size_t)(3*3 + 2)*65536 + t*32 + r];
        sv[e] = s;
        run = fmaxf(run, s);
        v[e] = run;
    }
    part[tid] = run;
    __syncthreads();
    for (int off = 1; off < 256; off <<= 1) {
        float other = (tid >= off) ? part[tid - off] : -INFINITY;
        __syncthreads();
        part[tid] = fmaxf(part[tid], other);
        __syncthreads();
    }
    float excl = (tid > 0) ? part[tid - 1] : -INFINITY;
#pragma unroll
    for (int e = 0; e < 8; ++e) {
        int t = t0 + e;
        ms[t*32 + r] = fmaxf(v[e], excl);
        evtb[(size_t)r * 2048 + t] = f2b(expf(sv[e]));
    }
}

// ---------------------------------------------------------------------------
// Packed dispatch B: seed_mfma (256 blocks, tri-masked) + near_fused (384)
// ---------------------------------------------------------------------------
__device__ void seed_body(int it, int jc, unsigned char* smem,
    const unsigned short* __restrict__ qrb, const unsigned short* __restrict__ krb,
    const unsigned short* __restrict__ evtb, float* __restrict__ partial)
{
    const int i0 = it * 128, j0 = jc * 128;
    unsigned short* Qs = (unsigned short*)smem;             // 8 KB
    unsigned short* Ks = (unsigned short*)(smem + 8192);    // 8 KB
    unsigned short* Es = (unsigned short*)(smem + 16384);   // 8 KB
    unsigned short* Ps = (unsigned short*)(smem + 24576);   // 32 KB
    const int tid = threadIdx.x, lane = tid & 63, wid = tid >> 6;
    const int fr = lane & 15, fq = lane >> 4;

#pragma unroll
    for (int s = 0; s < 2; ++s) {
        int cb = s * 256 + wid * 64;
        int c = cb + lane;
        int r = c >> 2, col = (c & 3) * 8;
        gload16(qrb + (size_t)(i0 + r) * 32 + col, &Qs[cb * 8]);
        gload16(krb + (size_t)(j0 + r) * 32 + col, &Ks[cb * 8]);
    }
#pragma unroll
    for (int s = 0; s < 2; ++s) {
        int c = s * 256 + tid;
        int rr = c >> 4, cc = c & 15;
        bf16x8 v = *(const bf16x8*)&evtb[(size_t)rr * 2048 + j0 + cc * 8];
        int byte = (rr * 256 + cc * 16) ^ ((rr & 7) << 4);
        *(bf16x8*)((char*)Es + byte) = v;
    }
    __syncthreads();

    const int wr = wid >> 1, wc = wid & 1;
    bf16x8 af[4], bk[4];
#pragma unroll
    for (int mi = 0; mi < 4; ++mi)
        af[mi] = *(const bf16x8*)&Qs[(wr*64 + mi*16 + fr)*32 + fq*8];
#pragma unroll
    for (int ni = 0; ni < 4; ++ni)
        bk[ni] = *(const bf16x8*)&Ks[(wc*64 + ni*16 + fr)*32 + fq*8];
#pragma unroll
    for (int mi = 0; mi < 4; ++mi)
#pragma unroll
        for (int ni = 0; ni < 4; ++ni) {
            f32x4 s4 = __builtin_amdgcn_mfma_f32_16x16x32_bf16(
                af[mi], bk[ni], (f32x4){0.f,0.f,0.f,0.f}, 0, 0, 0);
#pragma unroll
            for (int v = 0; v < 4; ++v) {
                int row = wr*64 + mi*16 + fq*4 + v;
                int col = wc*64 + ni*16 + fr;
                float a = 0.f;
                if (j0 + col <= i0 + row) {
                    float s = s4[v];
                    a = 1.f / (1.f + expf(-(s*s + B_SCALAR)));
                }
                int byte = (row * 256 + col * 2) ^ ((row & 7) << 4);
                *(unsigned short*)((char*)Ps + byte) = f2b(a);
            }
        }
    __syncthreads();

    f32x4 yacc[2][2];
#pragma unroll
    for (int mi = 0; mi < 2; ++mi)
#pragma unroll
        for (int nf = 0; nf < 2; ++nf) yacc[mi][nf] = (f32x4){0.f,0.f,0.f,0.f};
#pragma unroll
    for (int ks = 0; ks < 4; ++ks) {
        bf16x8 pa[2], eb[2];
#pragma unroll
        for (int mi = 0; mi < 2; ++mi) {
            int row = wid*32 + mi*16 + fr;
            int byte = (row * 256 + ks * 64 + fq * 16) ^ ((row & 7) << 4);
            pa[mi] = *(const bf16x8*)((const char*)Ps + byte);
        }
#pragma unroll
        for (int nf = 0; nf < 2; ++nf) {
            int rrow = nf*16 + fr;
            int byte = (rrow * 256 + ks * 64 + fq * 16) ^ ((rrow & 7) << 4);
            eb[nf] = *(const bf16x8*)((const char*)Es + byte);
        }
#pragma unroll
        for (int mi = 0; mi < 2; ++mi)
#pragma unroll
            for (int nf = 0; nf < 2; ++nf)
                yacc[mi][nf] = __builtin_amdgcn_mfma_f32_16x16x32_bf16(
                    pa[mi], eb[nf], yacc[mi][nf], 0, 0, 0);
    }
    float* pout = partial + ((size_t)(it*16 + jc) * 128) * 32;
#pragma unroll
    for (int mi = 0; mi < 2; ++mi)
#pragma unroll
        for (int nf = 0; nf < 2; ++nf)
#pragma unroll
            for (int v = 0; v < 4; ++v) {
                int row = wid*32 + mi*16 + fq*4 + v;
                int col = nf*16 + fr;
                pout[row*32 + col] = yacc[mi][nf][v];
            }
}

__device__ void near_body(int it, int hh, unsigned char* smem,
    const unsigned short* __restrict__ qhatb, const unsigned short* __restrict__ khatb,
    const unsigned short* __restrict__ vexptb, const float* __restrict__ mnear,
    const float* __restrict__ gu, const float* __restrict__ gb,
    float* __restrict__ hn, unsigned short* __restrict__ htlb)
{
    unsigned short* Qs  = (unsigned short*)smem;             // 8 KB
    unsigned short* KPs = (unsigned short*)(smem + 8192);    // 24 KB
    unsigned short* Vst = (unsigned short*)(smem + 32768);   // 24 KB
    const int i0 = it * 64;
    const int tid = threadIdx.x, lane = tid & 63, wid = tid >> 6;
    const int fr = lane & 15, fq = lane >> 4;

#pragma unroll
    for (int i = 0; i < 2; ++i) {
        int cb = i * 256 + wid * 64, c = cb + lane;
        int r = c >> 3, col = ((c & 7) ^ (r & 7)) * 8;
        gload16(qhatb + (size_t)(i0 + r) * 768 + hh*64 + col, &Qs[cb * 8]);
    }
#pragma unroll
    for (int i = 0; i < 6; ++i) {
        int cb = i * 256 + wid * 64, c = cb + lane;
        int r = c >> 3, col = ((c & 7) ^ (r & 7)) * 8;
        int j = i0 - 128 + r; if (j < 0) j = 0;
        gload16(khatb + (size_t)j * 768 + hh*64 + col, &KPs[cb * 8]);
    }
#pragma unroll
    for (int i = 0; i < 6; ++i) {
        int cb = i * 256 + wid * 64, c = cb + lane;
        int d = c / 24, cc = c - d * 24;
        int ccp = (cc & 24) | ((cc & 7) ^ (d & 7));
        int t = i0 - 128 + ccp * 8; if (t < 0) t = 0;
        gload16(vexptb + (size_t)(hh*64 + d) * 2048 + t, &Vst[cb * 8]);
    }
    __syncthreads();

    f32x4 sacc[4][3];
#pragma unroll
    for (int mi = 0; mi < 4; ++mi)
#pragma unroll
        for (int ni = 0; ni < 3; ++ni) sacc[mi][ni] = (f32x4){0.f,0.f,0.f,0.f};
#pragma unroll
    for (int kt = 0; kt < 2; ++kt) {
        int kk = kt * 32;
        bf16x8 qa[4], kb[3];
#pragma unroll
        for (int mi = 0; mi < 4; ++mi)
            qa[mi] = frag128(Qs, mi*16 + fr, kk + fq*8);
#pragma unroll
        for (int ni = 0; ni < 3; ++ni)
            kb[ni] = frag128(KPs, wid*48 + ni*16 + fr, kk + fq*8);
#pragma unroll
        for (int mi = 0; mi < 4; ++mi)
#pragma unroll
            for (int ni = 0; ni < 3; ++ni)
                sacc[mi][ni] = __builtin_amdgcn_mfma_f32_16x16x32_bf16(
                    qa[mi], kb[ni], sacc[mi][ni], 0, 0, 0);
    }
    __syncthreads();

#pragma unroll
    for (int mi = 0; mi < 4; ++mi)
#pragma unroll
        for (int ni = 0; ni < 3; ++ni)
#pragma unroll
            for (int v = 0; v < 4; ++v) {
                int il = mi*16 + fq*4 + v;
                int jl = wid*48 + ni*16 + fr;
                float s = sacc[mi][ni][v];
                float a = 0.f;
                if (jl >= il && jl <= il + 128 && (i0 - 128 + jl) >= 0)
                    a = 1.f / (1.f + expf(-(s*s*INV_TAU + B_SCALAR)));
                int byte = (il * 384 + jl * 2) ^ ((il & 7) << 4);
                *(unsigned short*)((char*)KPs + byte) = f2b(a);
            }
    __syncthreads();

    f32x4 yacc[4];
#pragma unroll
    for (int nf = 0; nf < 4; ++nf) yacc[nf] = (f32x4){0.f,0.f,0.f,0.f};
#pragma unroll
    for (int ks = 0; ks < 6; ++ks) {
        int kk = ks * 32;
        bf16x8 pa = frag384(KPs, wid*16 + fr, kk + fq*8);
        bf16x8 vb[4];
#pragma unroll
        for (int nf = 0; nf < 4; ++nf)
            vb[nf] = frag384(Vst, nf*16 + fr, kk + fq*8);
#pragma unroll
        for (int nf = 0; nf < 4; ++nf)
            yacc[nf] = __builtin_amdgcn_mfma_f32_16x16x32_bf16(pa, vb[nf], yacc[nf], 0, 0, 0);
    }

    float hv[4][4];
    float sp[4] = {0.f, 0.f, 0.f, 0.f};
#pragma unroll
    for (int nf = 0; nf < 4; ++nf) {
        int d = nf*16 + fr;
        float guv = gu[hh*64 + d];
#pragma unroll
        for (int v = 0; v < 4; ++v) {
            int row = wid*16 + fq*4 + v;
            float y = yacc[nf][v];
            float h = logf(fmaxf(y, 1e-30f)) + mnear[(size_t)(i0 + row)*768 + hh*64 + d];
            hv[nf][v] = h;
            sp[v] = fmaf(h, guv, sp[v]);
        }
    }
#pragma unroll
    for (int off = 1; off < 16; off <<= 1) {
#pragma unroll
        for (int v = 0; v < 4; ++v) sp[v] += __shfl_xor(sp[v], off);
    }
    float gbh = gb[hh];
#pragma unroll
    for (int v = 0; v < 4; ++v) sp[v] = 1.f / (1.f + expf(-(sp[v] + gbh)));
#pragma unroll
    for (int nf = 0; nf < 4; ++nf)
#pragma unroll
        for (int v = 0; v < 4; ++v) {
            int row = wid*16 + fq*4 + v;
            int d = nf*16 + fr;
            size_t idx = (size_t)(i0 + row)*768 + hh*64 + d;
            float htl = hv[nf][v] * sp[v];
            hn[idx] = htl;
            htlb[idx] = f2b(htl);
        }
}

__global__ __launch_bounds__(256) void seednear_pack(
    const unsigned short* __restrict__ qrb, const unsigned short* __restrict__ krb,
    const unsigned short* __restrict__ evtb, float* __restrict__ partial,
    const unsigned short* __restrict__ qhatb, const unsigned short* __restrict__ khatb,
    const unsigned short* __restrict__ vexptb, const float* __restrict__ mnear,
    const float* __restrict__ gu, const float* __restrict__ gb,
    float* __restrict__ hn, unsigned short* __restrict__ htlb)
{
    __shared__ unsigned char smem[57344];
    int b = blockIdx.x;
    if (b < 256) {
        int it = b >> 4, jc = b & 15;
        if (jc > it) return;
        seed_body(it, jc, smem, qrb, krb, evtb, partial);
    } else {
        int idx = b - 256;
        near_body(idx & 31, idx >> 5, smem, qhatb, khatb, vexptb, mnear,
                  gu, gb, hn, htlb);
    }
}

// ---------------------------------------------------------------------------
// Fused: reduce seed partials + LASER log + H0 = Lr @ up_w (+ bf16 copy).
// ---------------------------------------------------------------------------
__global__ __launch_bounds__(256) void seed_up(
    const float* __restrict__ partial, const float* __restrict__ ms,
    const float* __restrict__ up, float* __restrict__ h0,
    unsigned short* __restrict__ h0b)
{
    __shared__ float ls[32];
    int t = blockIdx.x, tid = threadIdx.x;
    if (tid < 32) {
        int r = tid;
        int it = t >> 7, row = t & 127;
        float y = 0.f;
        for (int jjc = 0; jjc <= it; ++jjc)
            y += partial[(((size_t)(it*16 + jjc) * 128) + row) * 32 + r];
        float m = ms[t*32 + r];
        ls[r] = logf(fmaxf(y * expf(-m), 1e-30f)) + m;
    }
    __syncthreads();
    for (int c = tid; c < 768; c += 256) {
        float acc = 0.f;
#pragma unroll
        for (int rr = 0; rr < 32; ++rr) acc = fmaf(ls[rr], up[rr*768 + c], acc);
        h0[(size_t)t*768 + c] = acc;
        h0b[(size_t)t*768 + c] = f2b(acc);
    }
}

// ---------------------------------------------------------------------------
extern "C" void kernel_launch(void* const* d_in, const int* in_sizes, int n_in,
                              void* d_out, int out_size, void* d_ws, size_t ws_size,
                              hipStream_t stream)
{
    const float* x  = (const float*)d_in[0];
    const float* wq = (const float*)d_in[1];  const float* bq = (const float*)d_in[2];
    const float* wk = (const float*)d_in[3];  const float* bk = (const float*)d_in[4];
    const float* wv = (const float*)d_in[5];  const float* bv = (const float*)d_in[6];
    const float* wo = (const float*)d_in[7];  const float* bo = (const float*)d_in[8];
    const float* pq = (const float*)d_in[9];  const float* pk = (const float*)d_in[10];
    const float* pv = (const float*)d_in[11];
    const float* up = (const float*)d_in[12];
    const float* gu = (const float*)d_in[13]; const float* gb = (const float*)d_in[14];
    const float* wz = (const float*)d_in[15]; const float* bz = (const float*)d_in[16];
    float* out = (float*)d_out;

    float* w = (float*)d_ws;
    float* ms   = w; w += 2048*32;
    float* h0   = w; w += 2048*768;
    float* mnear= w; w += 2048*768;
    float* hn   = w; w += 2048*768;          // Htilde after near_fused
    float* partial = w; w += 16*16*128*32;   // seed partials
    float* pgemm = w; w += 4*2048*768;       // Wz (4) / Wo (2) split-K partials
    float* plr   = w; w += 4*3*2048*32;      // lowrank split-K partials
    float* bqkv = w; w += 2304;
    unsigned short* xb     = (unsigned short*)w; w += 2048*768/2;
    unsigned short* qkvb   = (unsigned short*)w; w += 2048*2304/2;
    unsigned short* wqkvT  = (unsigned short*)w; w += 2304*768/2;
    unsigned short* wzT    = (unsigned short*)w; w += 768*3072/2;
    unsigned short* woT    = (unsigned short*)w; w += 768*768/2;
    unsigned short* pT     = (unsigned short*)w; w += 3*32*768/2;
    unsigned short* h0b    = (unsigned short*)w; w += 2048*768/2;
    unsigned short* htlb   = (unsigned short*)w; w += 2048*768/2;
    unsigned short* houtb  = (unsigned short*)w; w += 2048*768/2;
    unsigned short* qrb    = (unsigned short*)w; w += 2048*32/2;
    unsigned short* krb    = (unsigned short*)w; w += 2048*32/2;
    unsigned short* evtb   = (unsigned short*)w; w += 32*2048/2;
    unsigned short* qhatb  = (unsigned short*)w; w += 2048*768/2;
    unsigned short* khatb  = (unsigned short*)w; w += 2048*768/2;
    unsigned short* vexptb = (unsigned short*)w; w += 768*2048/2;

    // 1) prep (single mega-dispatch)
    prep_all<<<6225, 256, 0, stream>>>(x, xb, wq, wk, wv, wqkvT, wz, wzT,
                                       wo, woT, pq, pk, pv, pT, bq, bk, bv, bqkv);

    // 2) QKV projections (bf16 out only), XCD-swizzled
    gemm_mfma<0,1><<<dim3(18,32,1), 256, 0, stream>>>(xb, nullptr, nullptr,
        wqkvT, bqkv, nullptr, qkvb, nullptr, 768, 2304);

    // 3) lowrank GEMM + head-norms + sliding-max (packed, bf16 source)
    lrns_pack<<<6720, 256, 0, stream>>>(qkvb, pT, plr, qhatb, khatb, mnear, vexptb);

    // 4) lowrank combine + cummax
    lowrank_post<<<544, 256, 0, stream>>>(plr, qrb, krb, evtb, ms);

    // 5) seed attention + near-field attention (packed)
    seednear_pack<<<640, 256, 0, stream>>>(qrb, krb, evtb, partial,
        qhatb, khatb, vexptb, mnear, gu, gb, hn, htlb);

    // 6) seed reduce + H0 up-projection
    seed_up<<<2048, 256, 0, stream>>>(partial, ms, up, h0, h0b);

    // 7) Wz GEMM (split-K=4, inline h0*htl piece), XCD-swizzled
    gemm_mfma<1,4><<<dim3(6,32,4), 256, 0, stream>>>(xb, h0b, htlb,
        wzT, nullptr, nullptr, nullptr, pgemm, 3072, 768);

    // 8) Wz combine + GRU blend
    wz_combine<<<1536, 256, 0, stream>>>(pgemm, bz, h0, hn, houtb);

    // 9) Wo GEMM (split-K=2), XCD-swizzled
    gemm_mfma<2,2><<<dim3(6,32,2), 256, 0, stream>>>(houtb, nullptr, nullptr,
        woT, nullptr, nullptr, nullptr, pgemm, 768, 768);

    // 10) Wo combine + bias -> out
    wo_combine<<<1536, 256, 0, stream>>>(pgemm, bo, out);
}